// Round 2
// baseline (636.114 us; speedup 1.0000x reference)
//
#include <hip/hip_runtime.h>
#include <math.h>

static constexpr int B  = 4;
static constexpr int S  = 2048;
static constexpr int D  = 1024;
static constexpr int H  = 16;
static constexpr int DFF = 4096;

typedef __attribute__((ext_vector_type(8))) short short8;
typedef __attribute__((ext_vector_type(8))) unsigned short ushort8;
typedef __attribute__((ext_vector_type(4))) unsigned short ushort4v;
typedef __attribute__((ext_vector_type(4))) float f32x4;

__device__ __forceinline__ float b2f(unsigned short u) {
  unsigned int x = ((unsigned int)u) << 16;
  float f;
  __builtin_memcpy(&f, &x, 4);
  return f;
}
__device__ __forceinline__ unsigned short f2b(float f) {
  unsigned int x;
  __builtin_memcpy(&x, &f, 4);
  x += 0x7fffu + ((x >> 16) & 1u);  // round-to-nearest-even
  return (unsigned short)(x >> 16);
}

__device__ __forceinline__ f32x4 mfma16(short8 a, short8 b, f32x4 c) {
  return __builtin_amdgcn_mfma_f32_16x16x32_bf16(a, b, c, 0, 0, 0);
}

// global -> LDS direct copy, 16B per lane (wave-uniform base + lane*16).
__device__ __forceinline__ void gload_lds16(const void* gsrc, void* ldst) {
  __builtin_amdgcn_global_load_lds(
      (__attribute__((address_space(1))) void*)(uintptr_t)gsrc,
      (__attribute__((address_space(3))) void*)ldst, 16, 0, 0);
}

#define LGK0 asm volatile("s_waitcnt lgkmcnt(0)" ::: "memory")
#define LGK8 asm volatile("s_waitcnt lgkmcnt(8)" ::: "memory")
#define VMC8 asm volatile("s_waitcnt vmcnt(8)" ::: "memory")
#define VMC0 asm volatile("s_waitcnt vmcnt(0)" ::: "memory")
#define SB0  __builtin_amdgcn_sched_barrier(0)
#define BAR  __builtin_amdgcn_s_barrier()
#define PRIO1 __builtin_amdgcn_s_setprio(1)
#define PRIO0 __builtin_amdgcn_s_setprio(0)

// ---------------------------------------------------------------------------
// Batched f32 -> bf16 convert: 6 segments, grid (maxblocks, 6)
// ---------------------------------------------------------------------------
struct CvtArgs {
  const float* s[6];
  unsigned short* d[6];
  int n[6];
};
__global__ __launch_bounds__(256) void convert6(CvtArgs a) {
  const int seg = blockIdx.y;
  const int i = (blockIdx.x * 256 + threadIdx.x) * 4;
  if (i < a.n[seg]) {
    f32x4 v = *(const f32x4*)(a.s[seg] + i);
    ushort4v o;
#pragma unroll
    for (int j = 0; j < 4; j++) o[j] = f2b(v[j]);
    *(ushort4v*)(a.d[seg] + i) = o;
  }
}

// ---------------------------------------------------------------------------
// Fused LayerNorm (f32 in -> bf16 out): alpha*(x-mean)/(std+eps)+beta, ddof=1
// ---------------------------------------------------------------------------
__global__ __launch_bounds__(256) void ln_fused(const float* __restrict__ x,
                                                const float* __restrict__ ap,
                                                const float* __restrict__ cp,
                                                unsigned short* __restrict__ out) {
  const int row = blockIdx.x, tid = threadIdx.x;
  const size_t base = (size_t)row * D;
  float v[4];
  float s = 0.f, sq = 0.f;
#pragma unroll
  for (int i = 0; i < 4; i++) {
    v[i] = x[base + tid + i * 256];
    s += v[i];
    sq += v[i] * v[i];
  }
#pragma unroll
  for (int o = 32; o > 0; o >>= 1) {
    s += __shfl_xor(s, o);
    sq += __shfl_xor(sq, o);
  }
  __shared__ __align__(16) float rs[4], rq[4];
  const int wave = tid >> 6, lane = tid & 63;
  if (lane == 0) {
    rs[wave] = s;
    rq[wave] = sq;
  }
  __syncthreads();
  const float S1 = rs[0] + rs[1] + rs[2] + rs[3];
  const float S2 = rq[0] + rq[1] + rq[2] + rq[3];
  const float mean = S1 * (1.f / 1024.f);
  const float var = fmaxf(0.f, (S2 - 1024.f * mean * mean) * (1.f / 1023.f));
  const float rstd = 1.f / (sqrtf(var) + 1e-6f);
  const float alpha = ap[0], beta = cp[0];
#pragma unroll
  for (int i = 0; i < 4; i++)
    out[base + tid + i * 256] = f2b(alpha * (v[i] - mean) * rstd + beta);
}

// ---------------------------------------------------------------------------
// 256x256 8-wave deep-pipelined bf16 GEMM. v2: balanced per-phase ds_reads
// (12/4/8/0 quadrant-first-use), staging split 4+4 across ph2/ph3, lgkmcnt(8)
// pre-drain in the 12-read phase. BK=64, 128KiB dbuf LDS, XOR chunk swizzle
// (inverse swizzle on global source, linear gload_lds dest), counted vmcnt(8).
// ---------------------------------------------------------------------------
__device__ __forceinline__ void stage_half(const unsigned short* p0,
                                           unsigned short* ldsbuf, int wave,
                                           size_t K64, int koff) {
#pragma unroll
  for (int j = 0; j < 4; j++)
    gload_lds16(p0 + j * K64 + koff, ldsbuf + j * 4096 + wave * 512);
}

template <int EPI>
__global__ __launch_bounds__(512, 2) void gemm256(
    const unsigned short* __restrict__ A, const unsigned short* __restrict__ W,
    const float* __restrict__ bias0, const float* __restrict__ bias1,
    const float* __restrict__ bias2, void* __restrict__ out,
    unsigned short* __restrict__ outK, unsigned short* __restrict__ outV,
    int M, int N, int K) {
  __shared__ __align__(16) unsigned short lds[2 * 32768];  // 128 KiB
  const int tid = threadIdx.x;
  const int lane = tid & 63, wave = tid >> 6;
  const int quad = lane >> 4, l16 = lane & 15;

  // XCD-aware bijective swizzle (only when grid % 8 == 0)
  const int nbx = gridDim.x;
  const int nwg = nbx * gridDim.y;
  int wg = blockIdx.y * nbx + blockIdx.x;
  if (!(nwg & 7)) wg = (wg & 7) * (nwg >> 3) + (wg >> 3);
  const int bx = wg % nbx, by = wg / nbx;
  const int m0 = by * 256, n0 = bx * 256;
  const int wm = wave >> 2, wn = wave & 3;  // 2(M) x 4(N) wave grid

  const int srow = wave * 8 + (lane >> 3);
  const int scol = ((lane & 7) ^ (lane >> 3)) * 8;
  const size_t K64 = (size_t)K * 64;
  const unsigned short* pA0 = A + (size_t)(m0 + srow) * K + scol;
  const unsigned short* pB0 = W + (size_t)(n0 + srow) * K + scol;

  const int xr = l16 & 7;
  const int aoff0 = ((0 + quad) ^ xr) * 8;
  const int aoff1 = ((4 + quad) ^ xr) * 8;
  const int arow = wm * 128 + l16;
  const int brow = wn * 64 + l16;

  f32x4 acc[8][4];
#pragma unroll
  for (int i = 0; i < 8; i++)
#pragma unroll
    for (int j = 0; j < 4; j++) acc[i][j] = {0.f, 0.f, 0.f, 0.f};

  const int nkt = K >> 6;
  // prologue: tiles 0,1 staged; wait tile0 (tile1's 8 stay in flight)
  stage_half(pA0, &lds[0], wave, K64, 0);
  stage_half(pB0, &lds[16384], wave, K64, 0);
  stage_half(pA0, &lds[32768], wave, K64, 64);
  stage_half(pB0, &lds[32768 + 16384], wave, K64, 64);
  VMC8;
  SB0;
  BAR;

  short8 af[4][2], bf[4][2];
  for (int t = 0; t < nkt; ++t) {
    const int p = t & 1;
    const unsigned short* Ab = &lds[p * 32768];
    const unsigned short* Bb = Ab + 16384;

    // ---- ph0: 12 reads (A0-3, B0-1); MFMA mt0-3 x nt0-1 ----
#pragma unroll
    for (int mt = 0; mt < 4; mt++) {
      af[mt][0] = *(const short8*)&Ab[(arow + mt * 16) * 64 + aoff0];
      af[mt][1] = *(const short8*)&Ab[(arow + mt * 16) * 64 + aoff1];
    }
#pragma unroll
    for (int nt = 0; nt < 2; nt++) {
      bf[nt][0] = *(const short8*)&Bb[(brow + nt * 16) * 64 + aoff0];
      bf[nt][1] = *(const short8*)&Bb[(brow + nt * 16) * 64 + aoff1];
    }
    LGK8;
    BAR;
    LGK0;
    SB0;
    PRIO1;
#pragma unroll
    for (int mt = 0; mt < 4; mt++)
#pragma unroll
      for (int nt = 0; nt < 2; nt++) {
        acc[mt][nt] = mfma16(af[mt][0], bf[nt][0], acc[mt][nt]);
        acc[mt][nt] = mfma16(af[mt][1], bf[nt][1], acc[mt][nt]);
      }
    PRIO0;
    BAR;
    // ---- ph1: 4 reads (B2-3); MFMA mt0-3 x nt2-3 ----
#pragma unroll
    for (int nt = 2; nt < 4; nt++) {
      bf[nt][0] = *(const short8*)&Bb[(brow + nt * 16) * 64 + aoff0];
      bf[nt][1] = *(const short8*)&Bb[(brow + nt * 16) * 64 + aoff1];
    }
    BAR;
    LGK0;
    SB0;
    PRIO1;
#pragma unroll
    for (int mt = 0; mt < 4; mt++)
#pragma unroll
      for (int nt = 2; nt < 4; nt++) {
        acc[mt][nt] = mfma16(af[mt][0], bf[nt][0], acc[mt][nt]);
        acc[mt][nt] = mfma16(af[mt][1], bf[nt][1], acc[mt][nt]);
      }
    PRIO0;
    BAR;
    // ---- ph2: 8 reads (A4-7); all cur reads drained -> stage A(t+2) ----
#pragma unroll
    for (int i = 0; i < 4; i++) {
      af[i][0] = *(const short8*)&Ab[(arow + 64 + i * 16) * 64 + aoff0];
      af[i][1] = *(const short8*)&Ab[(arow + 64 + i * 16) * 64 + aoff1];
    }
    LGK0;  // this wave's reads of cur complete before barrier
    SB0;
    BAR;   // => ALL waves' reads of cur complete; safe to overwrite
    if (t + 2 < nkt) stage_half(pA0, &lds[p * 32768], wave, K64, (t + 2) * 64);
    PRIO1;
#pragma unroll
    for (int i = 0; i < 4; i++)
#pragma unroll
      for (int nt = 0; nt < 2; nt++) {
        acc[4 + i][nt] = mfma16(af[i][0], bf[nt][0], acc[4 + i][nt]);
        acc[4 + i][nt] = mfma16(af[i][1], bf[nt][1], acc[4 + i][nt]);
      }
    PRIO0;
    BAR;
    // ---- ph3: stage B(t+2); MFMA mt4-7 x nt2-3; counted vmcnt ----
    if (t + 2 < nkt) stage_half(pB0, &lds[p * 32768 + 16384], wave, K64, (t + 2) * 64);
    PRIO1;
#pragma unroll
    for (int i = 0; i < 4; i++)
#pragma unroll
      for (int nt = 2; nt < 4; nt++) {
        acc[4 + i][nt] = mfma16(af[i][0], bf[nt][0], acc[4 + i][nt]);
        acc[4 + i][nt] = mfma16(af[i][1], bf[nt][1], acc[4 + i][nt]);
      }
    PRIO0;
    if (t + 2 < nkt) {
      VMC8;
    } else if (t + 1 < nkt) {
      VMC0;
    }
    SB0;
    BAR;
  }

  // ---- epilogue ----
  if (EPI == 4) {
    const int band = (n0 + wn * 64) >> 10;
    const float* bp = band == 0 ? bias0 : (band == 1 ? bias1 : bias2);
#pragma unroll
    for (int nt = 0; nt < 4; nt++) {
      const int col = n0 + wn * 64 + nt * 16 + l16;
      const int cl = col & 1023;
      const float bv = bp[cl];
#pragma unroll
      for (int mt = 0; mt < 8; mt++) {
#pragma unroll
        for (int r = 0; r < 4; r++) {
          const int row = m0 + wm * 128 + mt * 16 + quad * 4 + r;
          const float v = acc[mt][nt][r] + bv;
          if (band == 0)
            ((unsigned short*)out)[(size_t)row * 1024 + cl] = f2b(v);
          else if (band == 1)
            outK[(size_t)row * 1024 + cl] = f2b(v);
          else
            outV[((size_t)((row >> 11) * 1024 + cl)) * 2048 + (row & 2047)] = f2b(v);
        }
      }
    }
  } else {  // EPI == 2: relu -> bf16
#pragma unroll
    for (int nt = 0; nt < 4; nt++) {
      const int col = n0 + wn * 64 + nt * 16 + l16;
      const float bv = bias0[col];
#pragma unroll
      for (int mt = 0; mt < 8; mt++)
#pragma unroll
        for (int r = 0; r < 4; r++) {
          const int row = m0 + wm * 128 + mt * 16 + quad * 4 + r;
          ((unsigned short*)out)[(size_t)row * (size_t)N + col] =
              f2b(fmaxf(acc[mt][nt][r] + bv, 0.f));
        }
    }
  }
}

// ---------------------------------------------------------------------------
// Pure-bf16 GEMM (m97 structure): kept for N=1024 GEMMs (AO, FFN2).
// ---------------------------------------------------------------------------
template <int EPI>
__global__ __launch_bounds__(256) void gemm_bb(
    const unsigned short* __restrict__ A, const unsigned short* __restrict__ W,
    const float* __restrict__ bias0, const float* __restrict__ bias1,
    const float* __restrict__ bias2, const float* __restrict__ resid,
    void* __restrict__ out, unsigned short* __restrict__ outK,
    unsigned short* __restrict__ outV, int M, int N, int K, int ldw) {
  __shared__ __align__(16) unsigned short As[128 * 32];
  __shared__ __align__(16) unsigned short Bs[128 * 32];
  const int tid = threadIdx.x;
  const int lane = tid & 63, wave = tid >> 6;
  const int quad = lane >> 4, l16 = lane & 15;
  const int m0 = blockIdx.y * 128, n0 = blockIdx.x * 128;
  const int wm = (wave >> 1) * 64, wn = (wave & 1) * 64;

  f32x4 acc[4][4];
#pragma unroll
  for (int i = 0; i < 4; i++)
#pragma unroll
    for (int j = 0; j < 4; j++) acc[i][j] = {0.f, 0.f, 0.f, 0.f};

  const int rA = tid >> 2;       // 0..63 row within half-tile
  const int kc = (tid & 3) * 8;  // 8-elem (16B) chunk

  for (int k0 = 0; k0 < K; k0 += 32) {
    __syncthreads();
#pragma unroll
    for (int i = 0; i < 2; i++) {
      const int row = i * 64 + rA;
      gload_lds16(&A[(size_t)(m0 + row) * K + k0 + kc], &As[(i * 256 + wave * 64) * 8]);
      gload_lds16(&W[(size_t)(n0 + row) * ldw + k0 + kc], &Bs[(i * 256 + wave * 64) * 8]);
    }
    __syncthreads();
    short8 af[4], bf[4];
#pragma unroll
    for (int t = 0; t < 4; t++) {
      af[t] = *(const short8*)&As[(wm + t * 16 + l16) * 32 + quad * 8];
      bf[t] = *(const short8*)&Bs[(wn + t * 16 + l16) * 32 + quad * 8];
    }
#pragma unroll
    for (int mt = 0; mt < 4; mt++)
#pragma unroll
      for (int nt = 0; nt < 4; nt++) acc[mt][nt] = mfma16(af[mt], bf[nt], acc[mt][nt]);
  }

  if (EPI == 4) {
    const int band = (n0 + wn) >> 10;
    const float* bp = band == 0 ? bias0 : (band == 1 ? bias1 : bias2);
#pragma unroll
    for (int nt = 0; nt < 4; nt++) {
      const int col = n0 + wn + nt * 16 + l16;
      const int cl = col & 1023;
      const float bv = bp[cl];
#pragma unroll
      for (int mt = 0; mt < 4; mt++) {
#pragma unroll
        for (int r = 0; r < 4; r++) {
          const int row = m0 + wm + mt * 16 + quad * 4 + r;
          const float v = acc[mt][nt][r] + bv;
          if (band == 0)
            ((unsigned short*)out)[(size_t)row * 1024 + cl] = f2b(v);
          else if (band == 1)
            outK[(size_t)row * 1024 + cl] = f2b(v);
          else
            outV[((size_t)((row >> 11) * 1024 + cl)) * 2048 + (row & 2047)] = f2b(v);
        }
      }
    }
  } else {
#pragma unroll
    for (int nt = 0; nt < 4; nt++) {
      const int col = n0 + wn + nt * 16 + l16;
      const float bv = (EPI == 3) ? 0.f : bias0[col];
#pragma unroll
      for (int mt = 0; mt < 4; mt++) {
#pragma unroll
        for (int r = 0; r < 4; r++) {
          const int row = m0 + wm + mt * 16 + quad * 4 + r;
          const size_t idx = (size_t)row * N + col;
          float v = acc[mt][nt][r] + bv;
          if (EPI == 2) {
            v = fmaxf(v, 0.f);
            ((unsigned short*)out)[idx] = f2b(v);
          } else {
            v += resid[idx];
            ((float*)out)[idx] = v;
          }
        }
      }
    }
  }
}

// ---------------------------------------------------------------------------
// Flash attention v2: QBLK=32 per wave (128 q-rows/block, grid (S/128, B*H)),
// K/V staged via global_load_lds into linear [64][64] LDS with XOR chunk
// swizzle (inverse-swizzled global source + swizzled ds_read — rule 21),
// double-buffered, ONE barrier + vmcnt(0) per tile. K-frags hoisted across
// the two q-halves. MFMA layouts / softmax / Pb transpose unchanged.
// ---------------------------------------------------------------------------
__device__ __forceinline__ void attn_stage(const unsigned short* Kg,
                                           const unsigned short* Vg,
                                           unsigned short* Kd, unsigned short* Vd,
                                           int kt) {
  gload_lds16(Kg + (size_t)kt * 64 * D, Kd);
  gload_lds16(Kg + (size_t)kt * 64 * D + 8 * D, Kd + 8 * 64);
  gload_lds16(Vg + (size_t)kt * 64, Vd);
  gload_lds16(Vg + (size_t)kt * 64 + 8 * (size_t)S, Vd + 8 * 64);
}

__global__ __launch_bounds__(256) void attn_kernel(unsigned short* __restrict__ Q,
                                                   const unsigned short* __restrict__ Kb,
                                                   const unsigned short* __restrict__ VT,
                                                   const int* __restrict__ mask) {
  __shared__ __align__(16) unsigned short Ks[2][64 * 64];
  __shared__ __align__(16) unsigned short Vs[2][64 * 64];
  constexpr int PPAD = 72;
  __shared__ __align__(16) unsigned short Pb[4][16 * PPAD];

  const int tid = threadIdx.x, lane = tid & 63, wave = tid >> 6;
  const int quad = lane >> 4, l16 = lane & 15;
  const int q0 = blockIdx.x * 128;
  const int b = blockIdx.y >> 4, h = blockIdx.y & 15;

  // staging addresses: lane covers row (lane>>3) of an 8-row group,
  // global chunk pre-swizzled so LDS[r][c] holds logical chunk c^(r&7)
  const int sr = lane >> 3;
  const int sc8 = ((lane & 7) ^ sr) * 8;
  const unsigned short* Kg = Kb + ((size_t)b * S + wave * 16 + sr) * D + h * 64 + sc8;
  const unsigned short* Vg = VT + ((size_t)blockIdx.y * 64 + wave * 16 + sr) * S + sc8;
  unsigned short* Kd0 = &Ks[0][(wave * 16) * 64];
  unsigned short* Vd0 = &Vs[0][(wave * 16) * 64];
  unsigned short* Kd1 = &Ks[1][(wave * 16) * 64];
  unsigned short* Vd1 = &Vs[1][(wave * 16) * 64];

  attn_stage(Kg, Vg, Kd0, Vd0, 0);

  // Q fragments: two q-halves, wave owns rows [q0+wave*32, +31]
  short8 qf[2][2];
#pragma unroll
  for (int qh = 0; qh < 2; qh++) {
    const unsigned short* qp =
        &Q[((size_t)b * S + q0 + wave * 32 + qh * 16 + l16) * D + h * 64 + quad * 8];
    qf[qh][0] = *(const short8*)qp;
    qf[qh][1] = *(const short8*)(qp + 32);
  }

  float l_acc[2] = {0.f, 0.f};
  f32x4 o_acc[2][4];
#pragma unroll
  for (int qh = 0; qh < 2; qh++)
#pragma unroll
    for (int t = 0; t < 4; t++) o_acc[qh][t] = {0.f, 0.f, 0.f, 0.f};

  // swizzled read chunk offsets (r&7 = l16&7 for frag rows)
  const int xr = l16 & 7;
  const int c0 = (quad ^ xr) * 8;
  const int c1 = ((quad + 4) ^ xr) * 8;

  VMC0;
  SB0;
  BAR;

  for (int kt = 0; kt < S / 64; kt++) {
    const int cur = kt & 1;
    if (kt + 1 < S / 64)
      attn_stage(Kg, Vg, cur ? Kd0 : Kd1, cur ? Vd0 : Vd1, kt + 1);
    const int k0 = kt * 64;
    const unsigned short* Kc = Ks[cur];
    const unsigned short* Vc = Vs[cur];

    // mask biases (shared across q-halves)
    f32x4 mb[4];
#pragma unroll
    for (int nt = 0; nt < 4; nt++) {
      const int4 mv = *(const int4*)&mask[b * S + k0 + nt * 16 + quad * 4];
      mb[nt][0] = mv.x ? -12.f : -42.f;
      mb[nt][1] = mv.y ? -12.f : -42.f;
      mb[nt][2] = mv.z ? -12.f : -42.f;
      mb[nt][3] = mv.w ? -12.f : -42.f;
    }
    // K fragments (shared across q-halves)
    short8 kf[4][2];
#pragma unroll
    for (int nt = 0; nt < 4; nt++) {
      kf[nt][0] = *(const short8*)&Kc[(nt * 16 + l16) * 64 + c0];
      kf[nt][1] = *(const short8*)&Kc[(nt * 16 + l16) * 64 + c1];
    }

#pragma unroll
    for (int qh = 0; qh < 2; qh++) {
      // S^T = K Q^T : C row = key quad*4+r (within nt tile), col = q = l16
      f32x4 sc4[4];
#pragma unroll
      for (int nt = 0; nt < 4; nt++) sc4[nt] = {0.f, 0.f, 0.f, 0.f};
      PRIO1;
#pragma unroll
      for (int nt = 0; nt < 4; nt++) {
        sc4[nt] = mfma16(kf[nt][0], qf[qh][0], sc4[nt]);
        sc4[nt] = mfma16(kf[nt][1], qf[qh][1], sc4[nt]);
      }
      PRIO0;

      // p = exp(s*0.125 + bias); pack 4 keys -> one b64 write
#pragma unroll
      for (int nt = 0; nt < 4; nt++) {
        ushort4v pk;
        const float p0 = __expf(fmaf(sc4[nt][0], 0.125f, mb[nt][0]));
        const float p1 = __expf(fmaf(sc4[nt][1], 0.125f, mb[nt][1]));
        const float p2 = __expf(fmaf(sc4[nt][2], 0.125f, mb[nt][2]));
        const float p3 = __expf(fmaf(sc4[nt][3], 0.125f, mb[nt][3]));
        l_acc[qh] += p0 + p1 + p2 + p3;
        pk[0] = f2b(p0);
        pk[1] = f2b(p1);
        pk[2] = f2b(p2);
        pk[3] = f2b(p3);
        *(ushort4v*)&Pb[wave][l16 * PPAD + nt * 16 + quad * 4] = pk;
      }

      // P @ V: A = P (rows q=l16, keys minor), B = V^T fragments
      short8 pf0 = *(const short8*)&Pb[wave][l16 * PPAD + quad * 8];
      short8 pf1 = *(const short8*)&Pb[wave][l16 * PPAD + 32 + quad * 8];
      PRIO1;
#pragma unroll
      for (int nt = 0; nt < 4; nt++) {
        short8 vf0 = *(const short8*)&Vc[(nt * 16 + l16) * 64 + c0];
        short8 vf1 = *(const short8*)&Vc[(nt * 16 + l16) * 64 + c1];
        o_acc[qh][nt] = mfma16(pf0, vf0, o_acc[qh][nt]);
        o_acc[qh][nt] = mfma16(pf1, vf1, o_acc[qh][nt]);
      }
      PRIO0;
    }

    VMC0;  // next tile's stage landed (hidden under this tile's compute)
    SB0;
    BAR;
    SB0;
  }

  // l: sum across quads; then normalize + store per q-half
#pragma unroll
  for (int qh = 0; qh < 2; qh++) {
    float la = l_acc[qh];
    la += __shfl_xor(la, 16);
    la += __shfl_xor(la, 32);
#pragma unroll
    for (int r = 0; r < 4; r++) {
      const float lr = __shfl(la, quad * 4 + r);
      const float inv = 1.f / lr;
      const int q = q0 + wave * 32 + qh * 16 + quad * 4 + r;
#pragma unroll
      for (int nt = 0; nt < 4; nt++) {
        const int dk = nt * 16 + l16;
        Q[((size_t)b * S + q) * D + h * 64 + dk] = f2b(o_acc[qh][nt][r] * inv);
      }
    }
  }
}

// ---------------------------------------------------------------------------
// FALLBACK path (ws < 89MB): round-5 kernels
// ---------------------------------------------------------------------------
__global__ __launch_bounds__(256) void stats_kernel(const float* __restrict__ x,
                                                    float2* __restrict__ st) {
  const int row = blockIdx.x, tid = threadIdx.x;
  const size_t base = (size_t)row * D;
  float s = 0.f, sq = 0.f;
#pragma unroll
  for (int i = 0; i < 4; i++) {
    const float v = x[base + tid + i * 256];
    s += v;
    sq += v * v;
  }
#pragma unroll
  for (int o = 32; o > 0; o >>= 1) {
    s += __shfl_xor(s, o);
    sq += __shfl_xor(sq, o);
  }
  __shared__ __align__(16) float rs[4], rq[4];
  const int wave = tid >> 6, lane = tid & 63;
  if (lane == 0) {
    rs[wave] = s;
    rq[wave] = sq;
  }
  __syncthreads();
  if (tid == 0) {
    const float S1 = rs[0] + rs[1] + rs[2] + rs[3];
    const float S2 = rq[0] + rq[1] + rq[2] + rq[3];
    const float mean = S1 * (1.f / 1024.f);
    const float var = fmaxf(0.f, (S2 - 1024.f * mean * mean) * (1.f / 1023.f));
    const float rstd = 1.f / (sqrtf(var) + 1e-6f);
    st[row] = make_float2(mean, rstd);
  }
}

template <int EPI, int NORM, int AF32, int OUTF32>
__global__ __launch_bounds__(256) void gemm_bt(
    const void* __restrict__ Ap, const float* __restrict__ W,
    const float* __restrict__ bias, const float* __restrict__ resid,
    void* __restrict__ outp, const float2* __restrict__ stats,
    const float* __restrict__ alpha_p, const float* __restrict__ beta_p,
    int M, int N, int K, int ldw) {
  __shared__ __align__(16) unsigned short As[128 * 32];
  __shared__ __align__(16) unsigned short Bs[128 * 32];
  const int tid = threadIdx.x;
  const int lane = tid & 63, wave = tid >> 6;
  const int quad = lane >> 4, l16 = lane & 15;
  const int m0 = blockIdx.y * 128, n0 = blockIdx.x * 128;
  const int wm = (wave >> 1) * 64, wn = (wave & 1) * 64;

  float alpha = 0.f, beta = 0.f;
  if (NORM) {
    alpha = alpha_p[0];
    beta = beta_p[0];
  }

  f32x4 acc[4][4];
#pragma unroll
  for (int i = 0; i < 4; i++)
#pragma unroll
    for (int j = 0; j < 4; j++) acc[i][j] = {0.f, 0.f, 0.f, 0.f};

  const int rA = tid >> 2;
  const int kc = (tid & 3) * 8;

  for (int k0 = 0; k0 < K; k0 += 32) {
    ushort8 av[2], bv8[2];
#pragma unroll
    for (int i = 0; i < 2; i++) {
      const int row = i * 64 + rA;
      if (AF32) {
        const float* ap = (const float*)Ap + (size_t)(m0 + row) * K + k0 + kc;
        f32x4 a0 = *(const f32x4*)ap;
        f32x4 a1 = *(const f32x4*)(ap + 4);
        if (NORM) {
          const float2 st = stats[m0 + row];
#pragma unroll
          for (int j = 0; j < 4; j++) {
            a0[j] = alpha * (a0[j] - st.x) * st.y + beta;
            a1[j] = alpha * (a1[j] - st.x) * st.y + beta;
          }
        }
#pragma unroll
        for (int j = 0; j < 4; j++) {
          av[i][j] = f2b(a0[j]);
          av[i][j + 4] = f2b(a1[j]);
        }
      } else {
        av[i] = *(const ushort8*)((const unsigned short*)Ap +
                                  (size_t)(m0 + row) * K + k0 + kc);
      }
      const float* wp = W + (size_t)(n0 + row) * ldw + k0 + kc;
      f32x4 w0 = *(const f32x4*)wp;
      f32x4 w1 = *(const f32x4*)(wp + 4);
#pragma unroll
      for (int j = 0; j < 4; j++) {
        bv8[i][j] = f2b(w0[j]);
        bv8[i][j + 4] = f2b(w1[j]);
      }
    }
    __syncthreads();
#pragma unroll
    for (int i = 0; i < 2; i++) {
      const int row = i * 64 + rA;
      *(ushort8*)&As[row * 32 + kc] = av[i];
      *(ushort8*)&Bs[row * 32 + kc] = bv8[i];
    }
    __syncthreads();
    short8 af[4], bf[4];
#pragma unroll
    for (int t = 0; t < 4; t++) {
      af[t] = *(const short8*)&As[(wm + t * 16 + l16) * 32 + quad * 8];
      bf[t] = *(const short8*)&Bs[(wn + t * 16 + l16) * 32 + quad * 8];
    }
#pragma unroll
    for (int mt = 0; mt < 4; mt++)
#pragma unroll
      for (int nt = 0; nt < 4; nt++) acc[mt][nt] = mfma16(af[mt], bf[nt], acc[mt][nt]);
  }

#pragma unroll
  for (int nt = 0; nt < 4; nt++) {
    const int col = n0 + wn + nt * 16 + l16;
    const float bv = (EPI == 3) ? 0.f : bias[col];
#pragma unroll
    for (int mt = 0; mt < 4; mt++) {
#pragma unroll
      for (int r = 0; r < 4; r++) {
        const int row = m0 + wm + mt * 16 + quad * 4 + r;
        float v = acc[mt][nt][r] + bv;
        if (EPI == 2) v = fmaxf(v, 0.f);
        if (EPI == 4) {
          const size_t vtidx =
              ((size_t)((row >> 11) * 1024 + col)) * 2048 + (row & 2047);
          ((unsigned short*)outp)[vtidx] = f2b(v);
        } else {
          const size_t idx = (size_t)row * N + col;
          if (EPI == 1 || EPI == 3) v += resid[idx];
          if (OUTF32)
            ((float*)outp)[idx] = v;
          else
            ((unsigned short*)outp)[idx] = f2b(v);
        }
      }
    }
  }
}

// ---------------------------------------------------------------------------
extern "C" void kernel_launch(void* const* d_in, const int* in_sizes, int n_in,
                              void* d_out, int out_size, void* d_ws, size_t ws_size,
                              hipStream_t stream) {
  (void)in_sizes; (void)n_in; (void)out_size;
  const float* x  = (const float*)d_in[0];
  const int* mask = (const int*)d_in[1];
  const float* wq = (const float*)d_in[2];
  const float* bq = (const float*)d_in[3];
  const float* wk = (const float*)d_in[4];
  const float* bk = (const float*)d_in[5];
  const float* wv = (const float*)d_in[6];
  const float* bv = (const float*)d_in[7];
  const float* wo = (const float*)d_in[8];
  const float* bo = (const float*)d_in[9];
  const float* w1 = (const float*)d_in[10];
  const float* b1 = (const float*)d_in[11];
  const float* w2 = (const float*)d_in[12];
  const float* b2 = (const float*)d_in[13];
  const float* a1 = (const float*)d_in[14];
  const float* c1 = (const float*)d_in[15];
  const float* a2 = (const float*)d_in[16];
  const float* c2 = (const float*)d_in[17];

  char* ws = (char*)d_ws;
  const size_t MB = 1 << 20;
  const int M = B * S;  // 8192
  dim3 blk(256);
  dim3 blk512(512);
  dim3 gAttn(S / 128, B * H);  // (16, 64)

  if (ws_size >= 89 * MB) {
    const int tier3 = (ws_size >= 152 * MB);
    const int tier2 = (ws_size >= 121 * MB);
    unsigned short* wqkv_b = (unsigned short*)(ws + 0);        // 6 MB
    unsigned short* wo_b   = (unsigned short*)(ws + 6 * MB);   // 2 MB
    unsigned short* w1_b   = (unsigned short*)(ws + 8 * MB);   // 8 MB
    unsigned short* w2_b   = (unsigned short*)(ws + 16 * MB);  // 8 MB
    unsigned short* ln1x   = (unsigned short*)(ws + 25 * MB);  // 16 MB
    unsigned short* q      = (unsigned short*)(ws + 41 * MB);  // 16 MB
    unsigned short* kk     = (unsigned short*)(ws + 57 * MB);  // 16 MB
    unsigned short* vt     = (unsigned short*)(ws + 73 * MB);  // 16 MB
    float*          hbuf   = (float*)(ws + 57 * MB);           // 32 MB (over kk+vt)
    unsigned short* ln2x   = (unsigned short*)(ws + 25 * MB);  // over ln1x
    unsigned short* ffn1q  = (unsigned short*)(ws + 41 * MB);  // over q (tier1)
    unsigned short* ffn1h  = (unsigned short*)(ws + 89 * MB);  // 32 MB (tier2)
    unsigned short* ffn1f  = (unsigned short*)(ws + 89 * MB);  // 64 MB (tier3)
    float* outb = (float*)d_out;

    // weights -> bf16, one batched dispatch
    CvtArgs ca;
    ca.s[0] = wq; ca.d[0] = wqkv_b;            ca.n[0] = 1048576;
    ca.s[1] = wk; ca.d[1] = wqkv_b + 1048576;  ca.n[1] = 1048576;
    ca.s[2] = wv; ca.d[2] = wqkv_b + 2097152;  ca.n[2] = 1048576;
    ca.s[3] = wo; ca.d[3] = wo_b;              ca.n[3] = 1048576;
    ca.s[4] = w1; ca.d[4] = w1_b;              ca.n[4] = 4194304;
    ca.s[5] = w2; ca.d[5] = w2_b;              ca.n[5] = 4194304;
    convert6<<<dim3(4096, 6), blk, 0, stream>>>(ca);

    ln_fused<<<M, blk, 0, stream>>>(x, a1, c1, ln1x);
    // QKV: 256^2 8-wave deep-pipelined kernel, grid (3072/256, 8192/256)
    gemm256<4><<<dim3(12, 32), blk512, 0, stream>>>(ln1x, wqkv_b, bq, bk, bv,
                                                    q, kk, vt, M, 3072, D);
    attn_kernel<<<gAttn, blk, 0, stream>>>(q, kk, vt, mask);
    gemm_bb<1><<<dim3(8, 64), blk, 0, stream>>>(q, wo_b, bo, nullptr, nullptr, x,
                                                hbuf, nullptr, nullptr, M, D, D, D);
    ln_fused<<<M, blk, 0, stream>>>(hbuf, a2, c2, ln2x);

    if (tier3) {
      // FFN1: 256^2 kernel, grid (4096/256, 8192/256) = 512 blocks (2 rounds)
      gemm256<2><<<dim3(16, 32), blk512, 0, stream>>>(ln2x, w1_b, b1, nullptr,
                                                      nullptr, ffn1f, nullptr,
                                                      nullptr, M, DFF, D);
      gemm_bb<1><<<dim3(8, 64), blk, 0, stream>>>(ffn1f, w2_b, b2, nullptr, nullptr,
                                                  hbuf, outb, nullptr, nullptr,
                                                  M, D, DFF, DFF);
    } else if (tier2) {
      gemm_bb<2><<<dim3(16, 64), blk, 0, stream>>>(ln2x, w1_b, b1, nullptr, nullptr,
                                                   nullptr, ffn1h, nullptr, nullptr,
                                                   M, 2048, D, D);
      gemm_bb<1><<<dim3(8, 64), blk, 0, stream>>>(ffn1h, w2_b, b2, nullptr, nullptr,
                                                  hbuf, outb, nullptr, nullptr,
                                                  M, D, 2048, DFF);
      gemm_bb<2><<<dim3(16, 64), blk, 0, stream>>>(ln2x, w1_b + (size_t)2048 * D,
                                                   b1 + 2048, nullptr, nullptr, nullptr,
                                                   ffn1h, nullptr, nullptr, M, 2048, D, D);
      gemm_bb<3><<<dim3(8, 64), blk, 0, stream>>>(ffn1h, w2_b + 2048, nullptr, nullptr,
                                                  nullptr, outb, outb, nullptr, nullptr,
                                                  M, D, 2048, DFF);
    } else {
      for (int i = 0; i < 4; i++) {
        gemm_bb<2><<<dim3(8, 64), blk, 0, stream>>>(ln2x, w1_b + (size_t)i * 1024 * D,
                                                    b1 + i * 1024, nullptr, nullptr,
                                                    nullptr, ffn1q, nullptr, nullptr,
                                                    M, 1024, D, D);
        if (i == 0)
          gemm_bb<1><<<dim3(8, 64), blk, 0, stream>>>(ffn1q, w2_b + i * 1024, b2, nullptr,
                                                      nullptr, hbuf, outb, nullptr, nullptr,
                                                      M, D, 1024, DFF);
        else
          gemm_bb<3><<<dim3(8, 64), blk, 0, stream>>>(ffn1q, w2_b + i * 1024, nullptr,
                                                      nullptr, nullptr, outb, outb, nullptr,
                                                      nullptr, M, D, 1024, DFF);
      }
    }
  } else {
    // fallback (round-5 structure, 49 MB peak)
    float2* stats1 = (float2*)(ws + 0);
    float2* stats2 = (float2*)(ws + 128 * 1024);
    unsigned short* q    = (unsigned short*)(ws + 1 * MB);
    unsigned short* kk   = (unsigned short*)(ws + 17 * MB);
    unsigned short* vt   = (unsigned short*)(ws + 33 * MB);
    float*          hbuf = (float*)(ws + 17 * MB);
    unsigned short* ffn1 = (unsigned short*)(ws + 1 * MB);
    float* outb = (float*)d_out;
    dim3 gD(D / 128, M / 128);

    stats_kernel<<<M, blk, 0, stream>>>(x, stats1);
    gemm_bt<0, 1, 1, 0><<<gD, blk, 0, stream>>>(x, wq, bq, nullptr, q, stats1, a1, c1, M, D, D, D);
    gemm_bt<0, 1, 1, 0><<<gD, blk, 0, stream>>>(x, wk, bk, nullptr, kk, stats1, a1, c1, M, D, D, D);
    gemm_bt<4, 1, 1, 0><<<gD, blk, 0, stream>>>(x, wv, bv, nullptr, vt, stats1, a1, c1, M, D, D, D);
    attn_kernel<<<gAttn, blk, 0, stream>>>(q, kk, vt, mask);
    gemm_bt<1, 0, 0, 1><<<gD, blk, 0, stream>>>(q, wo, bo, x, hbuf, nullptr, nullptr, nullptr, M, D, D, D);
    stats_kernel<<<M, blk, 0, stream>>>(hbuf, stats2);
    for (int i = 0; i < 4; i++) {
      gemm_bt<2, 1, 1, 0><<<gD, blk, 0, stream>>>(hbuf, w1 + (size_t)i * 1024 * D,
                                                  b1 + i * 1024, nullptr, ffn1, stats2,
                                                  a2, c2, M, 1024, D, D);
      if (i == 0)
        gemm_bt<1, 0, 0, 1><<<gD, blk, 0, stream>>>(ffn1, w2 + i * 1024, b2, hbuf, outb,
                                                    nullptr, nullptr, nullptr, M, D, 1024, DFF);
      else
        gemm_bt<3, 0, 0, 1><<<gD, blk, 0, stream>>>(ffn1, w2 + i * 1024, nullptr, outb, outb,
                                                    nullptr, nullptr, nullptr, M, D, 1024, DFF);
    }
  }
}

// Round 3
// 605.879 us; speedup vs baseline: 1.0499x; 1.0499x over previous
//
#include <hip/hip_runtime.h>
#include <math.h>

static constexpr int B  = 4;
static constexpr int S  = 2048;
static constexpr int D  = 1024;
static constexpr int H  = 16;
static constexpr int DFF = 4096;

typedef __attribute__((ext_vector_type(8))) short short8;
typedef __attribute__((ext_vector_type(8))) unsigned short ushort8;
typedef __attribute__((ext_vector_type(4))) unsigned short ushort4v;
typedef __attribute__((ext_vector_type(4))) float f32x4;

__device__ __forceinline__ float b2f(unsigned short u) {
  unsigned int x = ((unsigned int)u) << 16;
  float f;
  __builtin_memcpy(&f, &x, 4);
  return f;
}
__device__ __forceinline__ unsigned short f2b(float f) {
  unsigned int x;
  __builtin_memcpy(&x, &f, 4);
  x += 0x7fffu + ((x >> 16) & 1u);  // round-to-nearest-even
  return (unsigned short)(x >> 16);
}

// packed f32x2 -> bf16x2 (RNE), single VALU op (no builtin on gfx950)
__device__ __forceinline__ unsigned int cvtpk_bf16(float lo, float hi) {
  unsigned int r;
  asm("v_cvt_pk_bf16_f32 %0, %1, %2" : "=v"(r) : "v"(lo), "v"(hi));
  return r;
}

__device__ __forceinline__ f32x4 mfma16(short8 a, short8 b, f32x4 c) {
  return __builtin_amdgcn_mfma_f32_16x16x32_bf16(a, b, c, 0, 0, 0);
}

// global -> LDS direct copy, 16B per lane (wave-uniform base + lane*16).
__device__ __forceinline__ void gload_lds16(const void* gsrc, void* ldst) {
  __builtin_amdgcn_global_load_lds(
      (__attribute__((address_space(1))) void*)(uintptr_t)gsrc,
      (__attribute__((address_space(3))) void*)ldst, 16, 0, 0);
}

#define VMC0 asm volatile("s_waitcnt vmcnt(0)" ::: "memory")
#define SB0  __builtin_amdgcn_sched_barrier(0)
#define BAR  __builtin_amdgcn_s_barrier()
#define PRIO1 __builtin_amdgcn_s_setprio(1)
#define PRIO0 __builtin_amdgcn_s_setprio(0)

// ---------------------------------------------------------------------------
// Batched f32 -> bf16 convert: 6 segments, grid (maxblocks, 6)
// ---------------------------------------------------------------------------
struct CvtArgs {
  const float* s[6];
  unsigned short* d[6];
  int n[6];
};
__global__ __launch_bounds__(256) void convert6(CvtArgs a) {
  const int seg = blockIdx.y;
  const int i = (blockIdx.x * 256 + threadIdx.x) * 4;
  if (i < a.n[seg]) {
    f32x4 v = *(const f32x4*)(a.s[seg] + i);
    ushort4v o;
#pragma unroll
    for (int j = 0; j < 4; j++) o[j] = f2b(v[j]);
    *(ushort4v*)(a.d[seg] + i) = o;
  }
}

// ---------------------------------------------------------------------------
// Fused LayerNorm (f32 in -> bf16 out): alpha*(x-mean)/(std+eps)+beta, ddof=1
// ---------------------------------------------------------------------------
__global__ __launch_bounds__(256) void ln_fused(const float* __restrict__ x,
                                                const float* __restrict__ ap,
                                                const float* __restrict__ cp,
                                                unsigned short* __restrict__ out) {
  const int row = blockIdx.x, tid = threadIdx.x;
  const size_t base = (size_t)row * D;
  float v[4];
  float s = 0.f, sq = 0.f;
#pragma unroll
  for (int i = 0; i < 4; i++) {
    v[i] = x[base + tid + i * 256];
    s += v[i];
    sq += v[i] * v[i];
  }
#pragma unroll
  for (int o = 32; o > 0; o >>= 1) {
    s += __shfl_xor(s, o);
    sq += __shfl_xor(sq, o);
  }
  __shared__ __align__(16) float rs[4], rq[4];
  const int wave = tid >> 6, lane = tid & 63;
  if (lane == 0) {
    rs[wave] = s;
    rq[wave] = sq;
  }
  __syncthreads();
  const float S1 = rs[0] + rs[1] + rs[2] + rs[3];
  const float S2 = rq[0] + rq[1] + rq[2] + rq[3];
  const float mean = S1 * (1.f / 1024.f);
  const float var = fmaxf(0.f, (S2 - 1024.f * mean * mean) * (1.f / 1023.f));
  const float rstd = 1.f / (sqrtf(var) + 1e-6f);
  const float alpha = ap[0], beta = cp[0];
#pragma unroll
  for (int i = 0; i < 4; i++)
    out[base + tid + i * 256] = f2b(alpha * (v[i] - mean) * rstd + beta);
}

// ---------------------------------------------------------------------------
// Pure-bf16 GEMM (m97 structure): C = A @ W^T, global_load_lds 16B staging,
// 128x128 tile, BK=32, 4 waves, 4x4 MFMA frags.
// EPI 1: f32 out = acc + bias0 + f32 resid
// EPI 2: bf16 out = relu(acc + bias0)
// EPI 3: f32 out = acc + f32 resid              (no bias)
// EPI 4: QKV fused: col band 0 -> out (bf16), 1 -> outK (bf16),
//        2 -> outV transposed [(row>>11)*1024+cl][row&2047] (bf16)
// ---------------------------------------------------------------------------
template <int EPI>
__global__ __launch_bounds__(256) void gemm_bb(
    const unsigned short* __restrict__ A, const unsigned short* __restrict__ W,
    const float* __restrict__ bias0, const float* __restrict__ bias1,
    const float* __restrict__ bias2, const float* __restrict__ resid,
    void* __restrict__ out, unsigned short* __restrict__ outK,
    unsigned short* __restrict__ outV, int M, int N, int K, int ldw) {
  __shared__ __align__(16) unsigned short As[128 * 32];
  __shared__ __align__(16) unsigned short Bs[128 * 32];
  const int tid = threadIdx.x;
  const int lane = tid & 63, wave = tid >> 6;
  const int quad = lane >> 4, l16 = lane & 15;
  const int m0 = blockIdx.y * 128, n0 = blockIdx.x * 128;
  const int wm = (wave >> 1) * 64, wn = (wave & 1) * 64;

  f32x4 acc[4][4];
#pragma unroll
  for (int i = 0; i < 4; i++)
#pragma unroll
    for (int j = 0; j < 4; j++) acc[i][j] = {0.f, 0.f, 0.f, 0.f};

  const int rA = tid >> 2;       // 0..63 row within half-tile
  const int kc = (tid & 3) * 8;  // 8-elem (16B) chunk

  for (int k0 = 0; k0 < K; k0 += 32) {
    __syncthreads();
#pragma unroll
    for (int i = 0; i < 2; i++) {
      const int row = i * 64 + rA;
      gload_lds16(&A[(size_t)(m0 + row) * K + k0 + kc], &As[(i * 256 + wave * 64) * 8]);
      gload_lds16(&W[(size_t)(n0 + row) * ldw + k0 + kc], &Bs[(i * 256 + wave * 64) * 8]);
    }
    __syncthreads();
    short8 af[4], bf[4];
#pragma unroll
    for (int t = 0; t < 4; t++) {
      af[t] = *(const short8*)&As[(wm + t * 16 + l16) * 32 + quad * 8];
      bf[t] = *(const short8*)&Bs[(wn + t * 16 + l16) * 32 + quad * 8];
    }
#pragma unroll
    for (int mt = 0; mt < 4; mt++)
#pragma unroll
      for (int nt = 0; nt < 4; nt++) acc[mt][nt] = mfma16(af[mt], bf[nt], acc[mt][nt]);
  }

  if (EPI == 4) {
    const int band = (n0 + wn) >> 10;
    const float* bp = band == 0 ? bias0 : (band == 1 ? bias1 : bias2);
#pragma unroll
    for (int nt = 0; nt < 4; nt++) {
      const int col = n0 + wn + nt * 16 + l16;
      const int cl = col & 1023;
      const float bv = bp[cl];
#pragma unroll
      for (int mt = 0; mt < 4; mt++) {
#pragma unroll
        for (int r = 0; r < 4; r++) {
          const int row = m0 + wm + mt * 16 + quad * 4 + r;
          const float v = acc[mt][nt][r] + bv;
          if (band == 0)
            ((unsigned short*)out)[(size_t)row * 1024 + cl] = f2b(v);
          else if (band == 1)
            outK[(size_t)row * 1024 + cl] = f2b(v);
          else
            outV[((size_t)((row >> 11) * 1024 + cl)) * 2048 + (row & 2047)] = f2b(v);
        }
      }
    }
  } else {
#pragma unroll
    for (int nt = 0; nt < 4; nt++) {
      const int col = n0 + wn + nt * 16 + l16;
      const float bv = (EPI == 3) ? 0.f : bias0[col];
#pragma unroll
      for (int mt = 0; mt < 4; mt++) {
#pragma unroll
        for (int r = 0; r < 4; r++) {
          const int row = m0 + wm + mt * 16 + quad * 4 + r;
          const size_t idx = (size_t)row * N + col;
          float v = acc[mt][nt][r] + bv;
          if (EPI == 2) {
            v = fmaxf(v, 0.f);
            ((unsigned short*)out)[idx] = f2b(v);
          } else {
            v += resid[idx];
            ((float*)out)[idx] = v;
          }
        }
      }
    }
  }
}

// ---------------------------------------------------------------------------
// Flash attention v3: round-1 structure (QBLK=16/wave, grid (S/64, B*H)),
// single-buffered [64][64] K/V staged via global_load_lds with XOR chunk
// swizzle (inverse-swizzled global source + swizzled ds_read, rule 21),
// cvt_pk_bf16 packing for P. LDS 25.6KB -> 6 blocks/CU cap.
// ---------------------------------------------------------------------------
__device__ __forceinline__ void attn_stage(const unsigned short* Kg,
                                           const unsigned short* Vg,
                                           unsigned short* Kd, unsigned short* Vd,
                                           int kt) {
  gload_lds16(Kg + (size_t)kt * 64 * D, Kd);
  gload_lds16(Kg + (size_t)kt * 64 * D + 8 * (size_t)D, Kd + 8 * 64);
  gload_lds16(Vg + (size_t)kt * 64, Vd);
  gload_lds16(Vg + (size_t)kt * 64 + 8 * (size_t)S, Vd + 8 * 64);
}

__global__ __launch_bounds__(256) void attn_kernel(unsigned short* __restrict__ Q,
                                                   const unsigned short* __restrict__ Kb,
                                                   const unsigned short* __restrict__ VT,
                                                   const int* __restrict__ mask) {
  __shared__ __align__(16) unsigned short Ks[64 * 64];
  __shared__ __align__(16) unsigned short Vs[64 * 64];
  constexpr int PPAD = 72;
  __shared__ __align__(16) unsigned short Pb[4][16 * PPAD];

  const int tid = threadIdx.x, lane = tid & 63, wave = tid >> 6;
  const int quad = lane >> 4, l16 = lane & 15;
  const int q0 = blockIdx.x * 64;
  const int b = blockIdx.y >> 4, h = blockIdx.y & 15;

  // staging: lane covers row (lane>>3) of an 8-row group, 16B chunk (lane&7);
  // global chunk pre-swizzled so LDS[r][c] holds logical chunk c^(r&7)
  const int sr = lane >> 3;
  const int sc8 = ((lane & 7) ^ sr) * 8;
  const unsigned short* Kg = Kb + ((size_t)b * S + wave * 16 + sr) * D + h * 64 + sc8;
  const unsigned short* Vg = VT + ((size_t)blockIdx.y * 64 + wave * 16 + sr) * S + sc8;
  unsigned short* Kd = &Ks[(wave * 16) * 64];
  unsigned short* Vd = &Vs[(wave * 16) * 64];

  // Q fragment (B-operand): lane holds Q[q0+wave*16+l16][quad*8..+7 (+32)]
  short8 qf0, qf1;
  {
    const int qr = q0 + wave * 16 + l16;
    const unsigned short* qp = &Q[((size_t)(b * S) + qr) * D + h * 64 + quad * 8];
    qf0 = *(const short8*)qp;
    qf1 = *(const short8*)(qp + 32);
  }

  float l_acc = 0.f;  // partial sum for q = l16
  f32x4 o_acc[4];
#pragma unroll
  for (int t = 0; t < 4; t++) o_acc[t] = {0.f, 0.f, 0.f, 0.f};

  // swizzled read chunk offsets (r&7 = l16&7 for frag rows)
  const int xr = l16 & 7;
  const int c0 = (quad ^ xr) * 8;
  const int c1 = ((quad + 4) ^ xr) * 8;

  for (int kt = 0; kt < S / 64; kt++) {
    const int k0 = kt * 64;
    BAR;  // all waves' reads of previous tile complete (no-op cost on kt=0)
    attn_stage(Kg, Vg, Kd, Vd, kt);
    VMC0;
    SB0;
    BAR;  // staged data visible to all waves

    // S^T = K Q^T: C row = key quad*4+r (within nt tile), col = q = l16
    f32x4 sc4[4];
#pragma unroll
    for (int nt = 0; nt < 4; nt++) sc4[nt] = {0.f, 0.f, 0.f, 0.f};
    PRIO1;
#pragma unroll
    for (int nt = 0; nt < 4; nt++) {
      short8 kf0 = *(const short8*)&Ks[(nt * 16 + l16) * 64 + c0];
      short8 kf1 = *(const short8*)&Ks[(nt * 16 + l16) * 64 + c1];
      sc4[nt] = mfma16(kf0, qf0, sc4[nt]);
      sc4[nt] = mfma16(kf1, qf1, sc4[nt]);
    }
    PRIO0;

    // p = exp(s*0.125 - 12) (masked: -42); cvt_pk pack, one b64 write
#pragma unroll
    for (int nt = 0; nt < 4; nt++) {
      const int4 mv = *(const int4*)&mask[b * S + k0 + nt * 16 + quad * 4];
      const float p0 = __expf(fmaf(sc4[nt][0], 0.125f, mv.x ? -12.f : -42.f));
      const float p1 = __expf(fmaf(sc4[nt][1], 0.125f, mv.y ? -12.f : -42.f));
      const float p2 = __expf(fmaf(sc4[nt][2], 0.125f, mv.z ? -12.f : -42.f));
      const float p3 = __expf(fmaf(sc4[nt][3], 0.125f, mv.w ? -12.f : -42.f));
      l_acc += (p0 + p1) + (p2 + p3);
      uint2 pw;
      pw.x = cvtpk_bf16(p0, p1);
      pw.y = cvtpk_bf16(p2, p3);
      *(uint2*)&Pb[wave][l16 * PPAD + nt * 16 + quad * 4] = pw;
    }

    // P @ V: A = P (rows q=l16, keys minor), B = V^T fragments
    short8 pf0 = *(const short8*)&Pb[wave][l16 * PPAD + quad * 8];
    short8 pf1 = *(const short8*)&Pb[wave][l16 * PPAD + 32 + quad * 8];
    PRIO1;
#pragma unroll
    for (int nt = 0; nt < 4; nt++) {
      short8 vf0 = *(const short8*)&Vs[(nt * 16 + l16) * 64 + c0];
      short8 vf1 = *(const short8*)&Vs[(nt * 16 + l16) * 64 + c1];
      o_acc[nt] = mfma16(pf0, vf0, o_acc[nt]);
      o_acc[nt] = mfma16(pf1, vf1, o_acc[nt]);
    }
    PRIO0;
  }

  // l: sum across quads (all lanes end with total for q = l16)
  l_acc += __shfl_xor(l_acc, 16);
  l_acc += __shfl_xor(l_acc, 32);

  // normalize + store (PV C layout: row=q quad*4+r, col=dk nt*16+l16)
#pragma unroll
  for (int r = 0; r < 4; r++) {
    const float lr = __shfl(l_acc, quad * 4 + r);
    const float inv = 1.f / lr;
    const int q = q0 + wave * 16 + quad * 4 + r;
#pragma unroll
    for (int nt = 0; nt < 4; nt++) {
      const int dk = nt * 16 + l16;
      Q[((size_t)(b * S) + q) * D + h * 64 + dk] = f2b(o_acc[nt][r] * inv);
    }
  }
}

// ---------------------------------------------------------------------------
// FALLBACK path (ws < 89MB): round-5 kernels
// ---------------------------------------------------------------------------
__global__ __launch_bounds__(256) void stats_kernel(const float* __restrict__ x,
                                                    float2* __restrict__ st) {
  const int row = blockIdx.x, tid = threadIdx.x;
  const size_t base = (size_t)row * D;
  float s = 0.f, sq = 0.f;
#pragma unroll
  for (int i = 0; i < 4; i++) {
    const float v = x[base + tid + i * 256];
    s += v;
    sq += v * v;
  }
#pragma unroll
  for (int o = 32; o > 0; o >>= 1) {
    s += __shfl_xor(s, o);
    sq += __shfl_xor(sq, o);
  }
  __shared__ __align__(16) float rs[4], rq[4];
  const int wave = tid >> 6, lane = tid & 63;
  if (lane == 0) {
    rs[wave] = s;
    rq[wave] = sq;
  }
  __syncthreads();
  if (tid == 0) {
    const float S1 = rs[0] + rs[1] + rs[2] + rs[3];
    const float S2 = rq[0] + rq[1] + rq[2] + rq[3];
    const float mean = S1 * (1.f / 1024.f);
    const float var = fmaxf(0.f, (S2 - 1024.f * mean * mean) * (1.f / 1023.f));
    const float rstd = 1.f / (sqrtf(var) + 1e-6f);
    st[row] = make_float2(mean, rstd);
  }
}

template <int EPI, int NORM, int AF32, int OUTF32>
__global__ __launch_bounds__(256) void gemm_bt(
    const void* __restrict__ Ap, const float* __restrict__ W,
    const float* __restrict__ bias, const float* __restrict__ resid,
    void* __restrict__ outp, const float2* __restrict__ stats,
    const float* __restrict__ alpha_p, const float* __restrict__ beta_p,
    int M, int N, int K, int ldw) {
  __shared__ __align__(16) unsigned short As[128 * 32];
  __shared__ __align__(16) unsigned short Bs[128 * 32];
  const int tid = threadIdx.x;
  const int lane = tid & 63, wave = tid >> 6;
  const int quad = lane >> 4, l16 = lane & 15;
  const int m0 = blockIdx.y * 128, n0 = blockIdx.x * 128;
  const int wm = (wave >> 1) * 64, wn = (wave & 1) * 64;

  float alpha = 0.f, beta = 0.f;
  if (NORM) {
    alpha = alpha_p[0];
    beta = beta_p[0];
  }

  f32x4 acc[4][4];
#pragma unroll
  for (int i = 0; i < 4; i++)
#pragma unroll
    for (int j = 0; j < 4; j++) acc[i][j] = {0.f, 0.f, 0.f, 0.f};

  const int rA = tid >> 2;
  const int kc = (tid & 3) * 8;

  for (int k0 = 0; k0 < K; k0 += 32) {
    ushort8 av[2], bv8[2];
#pragma unroll
    for (int i = 0; i < 2; i++) {
      const int row = i * 64 + rA;
      if (AF32) {
        const float* ap = (const float*)Ap + (size_t)(m0 + row) * K + k0 + kc;
        f32x4 a0 = *(const f32x4*)ap;
        f32x4 a1 = *(const f32x4*)(ap + 4);
        if (NORM) {
          const float2 st = stats[m0 + row];
#pragma unroll
          for (int j = 0; j < 4; j++) {
            a0[j] = alpha * (a0[j] - st.x) * st.y + beta;
            a1[j] = alpha * (a1[j] - st.x) * st.y + beta;
          }
        }
#pragma unroll
        for (int j = 0; j < 4; j++) {
          av[i][j] = f2b(a0[j]);
          av[i][j + 4] = f2b(a1[j]);
        }
      } else {
        av[i] = *(const ushort8*)((const unsigned short*)Ap +
                                  (size_t)(m0 + row) * K + k0 + kc);
      }
      const float* wp = W + (size_t)(n0 + row) * ldw + k0 + kc;
      f32x4 w0 = *(const f32x4*)wp;
      f32x4 w1 = *(const f32x4*)(wp + 4);
#pragma unroll
      for (int j = 0; j < 4; j++) {
        bv8[i][j] = f2b(w0[j]);
        bv8[i][j + 4] = f2b(w1[j]);
      }
    }
    __syncthreads();
#pragma unroll
    for (int i = 0; i < 2; i++) {
      const int row = i * 64 + rA;
      *(ushort8*)&As[row * 32 + kc] = av[i];
      *(ushort8*)&Bs[row * 32 + kc] = bv8[i];
    }
    __syncthreads();
    short8 af[4], bf[4];
#pragma unroll
    for (int t = 0; t < 4; t++) {
      af[t] = *(const short8*)&As[(wm + t * 16 + l16) * 32 + quad * 8];
      bf[t] = *(const short8*)&Bs[(wn + t * 16 + l16) * 32 + quad * 8];
    }
#pragma unroll
    for (int mt = 0; mt < 4; mt++)
#pragma unroll
      for (int nt = 0; nt < 4; nt++) acc[mt][nt] = mfma16(af[mt], bf[nt], acc[mt][nt]);
  }

#pragma unroll
  for (int nt = 0; nt < 4; nt++) {
    const int col = n0 + wn + nt * 16 + l16;
    const float bv = (EPI == 3) ? 0.f : bias[col];
#pragma unroll
    for (int mt = 0; mt < 4; mt++) {
#pragma unroll
      for (int r = 0; r < 4; r++) {
        const int row = m0 + wm + mt * 16 + quad * 4 + r;
        float v = acc[mt][nt][r] + bv;
        if (EPI == 2) v = fmaxf(v, 0.f);
        if (EPI == 4) {
          const size_t vtidx =
              ((size_t)((row >> 11) * 1024 + col)) * 2048 + (row & 2047);
          ((unsigned short*)outp)[vtidx] = f2b(v);
        } else {
          const size_t idx = (size_t)row * N + col;
          if (EPI == 1 || EPI == 3) v += resid[idx];
          if (OUTF32)
            ((float*)outp)[idx] = v;
          else
            ((unsigned short*)outp)[idx] = f2b(v);
        }
      }
    }
  }
}

// ---------------------------------------------------------------------------
extern "C" void kernel_launch(void* const* d_in, const int* in_sizes, int n_in,
                              void* d_out, int out_size, void* d_ws, size_t ws_size,
                              hipStream_t stream) {
  (void)in_sizes; (void)n_in; (void)out_size;
  const float* x  = (const float*)d_in[0];
  const int* mask = (const int*)d_in[1];
  const float* wq = (const float*)d_in[2];
  const float* bq = (const float*)d_in[3];
  const float* wk = (const float*)d_in[4];
  const float* bk = (const float*)d_in[5];
  const float* wv = (const float*)d_in[6];
  const float* bv = (const float*)d_in[7];
  const float* wo = (const float*)d_in[8];
  const float* bo = (const float*)d_in[9];
  const float* w1 = (const float*)d_in[10];
  const float* b1 = (const float*)d_in[11];
  const float* w2 = (const float*)d_in[12];
  const float* b2 = (const float*)d_in[13];
  const float* a1 = (const float*)d_in[14];
  const float* c1 = (const float*)d_in[15];
  const float* a2 = (const float*)d_in[16];
  const float* c2 = (const float*)d_in[17];

  char* ws = (char*)d_ws;
  const size_t MB = 1 << 20;
  const int M = B * S;  // 8192
  dim3 blk(256);
  dim3 gAttn(S / 64, B * H);  // (32, 64)

  if (ws_size >= 89 * MB) {
    const int tier3 = (ws_size >= 152 * MB);
    const int tier2 = (ws_size >= 121 * MB);
    unsigned short* wqkv_b = (unsigned short*)(ws + 0);        // 6 MB
    unsigned short* wo_b   = (unsigned short*)(ws + 6 * MB);   // 2 MB
    unsigned short* w1_b   = (unsigned short*)(ws + 8 * MB);   // 8 MB
    unsigned short* w2_b   = (unsigned short*)(ws + 16 * MB);  // 8 MB
    unsigned short* ln1x   = (unsigned short*)(ws + 25 * MB);  // 16 MB
    unsigned short* q      = (unsigned short*)(ws + 41 * MB);  // 16 MB
    unsigned short* kk     = (unsigned short*)(ws + 57 * MB);  // 16 MB
    unsigned short* vt     = (unsigned short*)(ws + 73 * MB);  // 16 MB
    float*          hbuf   = (float*)(ws + 57 * MB);           // 32 MB (over kk+vt)
    unsigned short* ln2x   = (unsigned short*)(ws + 25 * MB);  // over ln1x
    unsigned short* ffn1q  = (unsigned short*)(ws + 41 * MB);  // over q (tier1)
    unsigned short* ffn1h  = (unsigned short*)(ws + 89 * MB);  // 32 MB (tier2)
    unsigned short* ffn1f  = (unsigned short*)(ws + 89 * MB);  // 64 MB (tier3)
    float* outb = (float*)d_out;

    // weights -> bf16, one batched dispatch
    CvtArgs ca;
    ca.s[0] = wq; ca.d[0] = wqkv_b;            ca.n[0] = 1048576;
    ca.s[1] = wk; ca.d[1] = wqkv_b + 1048576;  ca.n[1] = 1048576;
    ca.s[2] = wv; ca.d[2] = wqkv_b + 2097152;  ca.n[2] = 1048576;
    ca.s[3] = wo; ca.d[3] = wo_b;              ca.n[3] = 1048576;
    ca.s[4] = w1; ca.d[4] = w1_b;              ca.n[4] = 4194304;
    ca.s[5] = w2; ca.d[5] = w2_b;              ca.n[5] = 4194304;
    convert6<<<dim3(4096, 6), blk, 0, stream>>>(ca);

    ln_fused<<<M, blk, 0, stream>>>(x, a1, c1, ln1x);
    gemm_bb<4><<<dim3(24, 64), blk, 0, stream>>>(ln1x, wqkv_b, bq, bk, bv, nullptr,
                                                 q, kk, vt, M, 3072, D, D);
    attn_kernel<<<gAttn, blk, 0, stream>>>(q, kk, vt, mask);
    gemm_bb<1><<<dim3(8, 64), blk, 0, stream>>>(q, wo_b, bo, nullptr, nullptr, x,
                                                hbuf, nullptr, nullptr, M, D, D, D);
    ln_fused<<<M, blk, 0, stream>>>(hbuf, a2, c2, ln2x);

    if (tier3) {
      // one full FFN1 (N=4096) + one full-K FFN2 (K=4096)
      gemm_bb<2><<<dim3(32, 64), blk, 0, stream>>>(ln2x, w1_b, b1, nullptr, nullptr,
                                                   nullptr, ffn1f, nullptr, nullptr,
                                                   M, DFF, D, D);
      gemm_bb<1><<<dim3(8, 64), blk, 0, stream>>>(ffn1f, w2_b, b2, nullptr, nullptr,
                                                  hbuf, outb, nullptr, nullptr,
                                                  M, D, DFF, DFF);
    } else if (tier2) {
      gemm_bb<2><<<dim3(16, 64), blk, 0, stream>>>(ln2x, w1_b, b1, nullptr, nullptr,
                                                   nullptr, ffn1h, nullptr, nullptr,
                                                   M, 2048, D, D);
      gemm_bb<1><<<dim3(8, 64), blk, 0, stream>>>(ffn1h, w2_b, b2, nullptr, nullptr,
                                                  hbuf, outb, nullptr, nullptr,
                                                  M, D, 2048, DFF);
      gemm_bb<2><<<dim3(16, 64), blk, 0, stream>>>(ln2x, w1_b + (size_t)2048 * D,
                                                   b1 + 2048, nullptr, nullptr, nullptr,
                                                   ffn1h, nullptr, nullptr, M, 2048, D, D);
      gemm_bb<3><<<dim3(8, 64), blk, 0, stream>>>(ffn1h, w2_b + 2048, nullptr, nullptr,
                                                  nullptr, outb, outb, nullptr, nullptr,
                                                  M, D, 2048, DFF);
    } else {
      for (int i = 0; i < 4; i++) {
        gemm_bb<2><<<dim3(8, 64), blk, 0, stream>>>(ln2x, w1_b + (size_t)i * 1024 * D,
                                                    b1 + i * 1024, nullptr, nullptr,
                                                    nullptr, ffn1q, nullptr, nullptr,
                                                    M, 1024, D, D);
        if (i == 0)
          gemm_bb<1><<<dim3(8, 64), blk, 0, stream>>>(ffn1q, w2_b + i * 1024, b2, nullptr,
                                                      nullptr, hbuf, outb, nullptr, nullptr,
                                                      M, D, 1024, DFF);
        else
          gemm_bb<3><<<dim3(8, 64), blk, 0, stream>>>(ffn1q, w2_b + i * 1024, nullptr,
                                                      nullptr, nullptr, outb, outb, nullptr,
                                                      nullptr, M, D, 1024, DFF);
      }
    }
  } else {
    // fallback (round-5 structure, 49 MB peak)
    float2* stats1 = (float2*)(ws + 0);
    float2* stats2 = (float2*)(ws + 128 * 1024);
    unsigned short* q    = (unsigned short*)(ws + 1 * MB);
    unsigned short* kk   = (unsigned short*)(ws + 17 * MB);
    unsigned short* vt   = (unsigned short*)(ws + 33 * MB);
    float*          hbuf = (float*)(ws + 17 * MB);
    unsigned short* ffn1 = (unsigned short*)(ws + 1 * MB);
    float* outb = (float*)d_out;
    dim3 gD(D / 128, M / 128);

    stats_kernel<<<M, blk, 0, stream>>>(x, stats1);
    gemm_bt<0, 1, 1, 0><<<gD, blk, 0, stream>>>(x, wq, bq, nullptr, q, stats1, a1, c1, M, D, D, D);
    gemm_bt<0, 1, 1, 0><<<gD, blk, 0, stream>>>(x, wk, bk, nullptr, kk, stats1, a1, c1, M, D, D, D);
    gemm_bt<4, 1, 1, 0><<<gD, blk, 0, stream>>>(x, wv, bv, nullptr, vt, stats1, a1, c1, M, D, D, D);
    attn_kernel<<<gAttn, blk, 0, stream>>>(q, kk, vt, mask);
    gemm_bt<1, 0, 0, 1><<<gD, blk, 0, stream>>>(q, wo, bo, x, hbuf, nullptr, nullptr, nullptr, M, D, D, D);
    stats_kernel<<<M, blk, 0, stream>>>(hbuf, stats2);
    for (int i = 0; i < 4; i++) {
      gemm_bt<2, 1, 1, 0><<<gD, blk, 0, stream>>>(hbuf, w1 + (size_t)i * 1024 * D,
                                                  b1 + i * 1024, nullptr, ffn1, stats2,
                                                  a2, c2, M, 1024, D, D);
      if (i == 0)
        gemm_bt<1, 0, 0, 1><<<gD, blk, 0, stream>>>(ffn1, w2 + i * 1024, b2, hbuf, outb,
                                                    nullptr, nullptr, nullptr, M, D, 1024, DFF);
      else
        gemm_bt<3, 0, 0, 1><<<gD, blk, 0, stream>>>(ffn1, w2 + i * 1024, nullptr, outb, outb,
                                                    nullptr, nullptr, nullptr, M, D, 1024, DFF);
    }
  }
}

// Round 4
// 596.039 us; speedup vs baseline: 1.0672x; 1.0165x over previous
//
#include <hip/hip_runtime.h>
#include <math.h>

static constexpr int B  = 4;
static constexpr int S  = 2048;
static constexpr int D  = 1024;
static constexpr int H  = 16;
static constexpr int DFF = 4096;

typedef __attribute__((ext_vector_type(8))) short short8;
typedef __attribute__((ext_vector_type(8))) unsigned short ushort8;
typedef __attribute__((ext_vector_type(4))) unsigned short ushort4v;
typedef __attribute__((ext_vector_type(4))) float f32x4;

__device__ __forceinline__ float b2f(unsigned short u) {
  unsigned int x = ((unsigned int)u) << 16;
  float f;
  __builtin_memcpy(&f, &x, 4);
  return f;
}
__device__ __forceinline__ unsigned short f2b(float f) {
  unsigned int x;
  __builtin_memcpy(&x, &f, 4);
  x += 0x7fffu + ((x >> 16) & 1u);  // round-to-nearest-even
  return (unsigned short)(x >> 16);
}

// packed f32x2 -> bf16x2 (RNE), single VALU op (no builtin on gfx950)
__device__ __forceinline__ unsigned int cvtpk_bf16(float lo, float hi) {
  unsigned int r;
  asm("v_cvt_pk_bf16_f32 %0, %1, %2" : "=v"(r) : "v"(lo), "v"(hi));
  return r;
}

__device__ __forceinline__ f32x4 mfma16(short8 a, short8 b, f32x4 c) {
  return __builtin_amdgcn_mfma_f32_16x16x32_bf16(a, b, c, 0, 0, 0);
}

// global -> LDS direct copy, 16B per lane (wave-uniform base + lane*16).
__device__ __forceinline__ void gload_lds16(const void* gsrc, void* ldst) {
  __builtin_amdgcn_global_load_lds(
      (__attribute__((address_space(1))) void*)(uintptr_t)gsrc,
      (__attribute__((address_space(3))) void*)ldst, 16, 0, 0);
}

#define VMC0 asm volatile("s_waitcnt vmcnt(0)" ::: "memory")
#define SB0  __builtin_amdgcn_sched_barrier(0)
#define BAR  __builtin_amdgcn_s_barrier()
#define PRIO1 __builtin_amdgcn_s_setprio(1)
#define PRIO0 __builtin_amdgcn_s_setprio(0)

// ---------------------------------------------------------------------------
// Batched f32 -> bf16 convert: 6 segments, grid (maxblocks, 6)
// ---------------------------------------------------------------------------
struct CvtArgs {
  const float* s[6];
  unsigned short* d[6];
  int n[6];
};
__global__ __launch_bounds__(256) void convert6(CvtArgs a) {
  const int seg = blockIdx.y;
  const int i = (blockIdx.x * 256 + threadIdx.x) * 4;
  if (i < a.n[seg]) {
    f32x4 v = *(const f32x4*)(a.s[seg] + i);
    ushort4v o;
#pragma unroll
    for (int j = 0; j < 4; j++) o[j] = f2b(v[j]);
    *(ushort4v*)(a.d[seg] + i) = o;
  }
}

// ---------------------------------------------------------------------------
// Fused LayerNorm (f32 in -> bf16 out): alpha*(x-mean)/(std+eps)+beta, ddof=1
// ---------------------------------------------------------------------------
__global__ __launch_bounds__(256) void ln_fused(const float* __restrict__ x,
                                                const float* __restrict__ ap,
                                                const float* __restrict__ cp,
                                                unsigned short* __restrict__ out) {
  const int row = blockIdx.x, tid = threadIdx.x;
  const size_t base = (size_t)row * D;
  float v[4];
  float s = 0.f, sq = 0.f;
#pragma unroll
  for (int i = 0; i < 4; i++) {
    v[i] = x[base + tid + i * 256];
    s += v[i];
    sq += v[i] * v[i];
  }
#pragma unroll
  for (int o = 32; o > 0; o >>= 1) {
    s += __shfl_xor(s, o);
    sq += __shfl_xor(sq, o);
  }
  __shared__ __align__(16) float rs[4], rq[4];
  const int wave = tid >> 6, lane = tid & 63;
  if (lane == 0) {
    rs[wave] = s;
    rq[wave] = sq;
  }
  __syncthreads();
  const float S1 = rs[0] + rs[1] + rs[2] + rs[3];
  const float S2 = rq[0] + rq[1] + rq[2] + rq[3];
  const float mean = S1 * (1.f / 1024.f);
  const float var = fmaxf(0.f, (S2 - 1024.f * mean * mean) * (1.f / 1023.f));
  const float rstd = 1.f / (sqrtf(var) + 1e-6f);
  const float alpha = ap[0], beta = cp[0];
#pragma unroll
  for (int i = 0; i < 4; i++)
    out[base + tid + i * 256] = f2b(alpha * (v[i] - mean) * rstd + beta);
}

// ---------------------------------------------------------------------------
// Pure-bf16 GEMM (m97 structure): C = A @ W^T, global_load_lds 16B staging,
// 128x128 tile, BK=32, 4 waves, 4x4 MFMA frags.
// EPI 1: f32 out = acc + bias0 + f32 resid
// EPI 2: bf16 out = relu(acc + bias0)
// EPI 3: f32 out = acc + f32 resid              (no bias)
// EPI 4: QKV fused: col band 0 -> out (bf16), 1 -> outK (bf16),
//        2 -> outV transposed [(row>>11)*1024+cl][row&2047] (bf16)
// ---------------------------------------------------------------------------
template <int EPI>
__global__ __launch_bounds__(256) void gemm_bb(
    const unsigned short* __restrict__ A, const unsigned short* __restrict__ W,
    const float* __restrict__ bias0, const float* __restrict__ bias1,
    const float* __restrict__ bias2, const float* __restrict__ resid,
    void* __restrict__ out, unsigned short* __restrict__ outK,
    unsigned short* __restrict__ outV, int M, int N, int K, int ldw) {
  __shared__ __align__(16) unsigned short As[128 * 32];
  __shared__ __align__(16) unsigned short Bs[128 * 32];
  const int tid = threadIdx.x;
  const int lane = tid & 63, wave = tid >> 6;
  const int quad = lane >> 4, l16 = lane & 15;
  const int m0 = blockIdx.y * 128, n0 = blockIdx.x * 128;
  const int wm = (wave >> 1) * 64, wn = (wave & 1) * 64;

  f32x4 acc[4][4];
#pragma unroll
  for (int i = 0; i < 4; i++)
#pragma unroll
    for (int j = 0; j < 4; j++) acc[i][j] = {0.f, 0.f, 0.f, 0.f};

  const int rA = tid >> 2;       // 0..63 row within half-tile
  const int kc = (tid & 3) * 8;  // 8-elem (16B) chunk

  for (int k0 = 0; k0 < K; k0 += 32) {
    __syncthreads();
#pragma unroll
    for (int i = 0; i < 2; i++) {
      const int row = i * 64 + rA;
      gload_lds16(&A[(size_t)(m0 + row) * K + k0 + kc], &As[(i * 256 + wave * 64) * 8]);
      gload_lds16(&W[(size_t)(n0 + row) * ldw + k0 + kc], &Bs[(i * 256 + wave * 64) * 8]);
    }
    __syncthreads();
    short8 af[4], bf[4];
#pragma unroll
    for (int t = 0; t < 4; t++) {
      af[t] = *(const short8*)&As[(wm + t * 16 + l16) * 32 + quad * 8];
      bf[t] = *(const short8*)&Bs[(wn + t * 16 + l16) * 32 + quad * 8];
    }
#pragma unroll
    for (int mt = 0; mt < 4; mt++)
#pragma unroll
      for (int nt = 0; nt < 4; nt++) acc[mt][nt] = mfma16(af[mt], bf[nt], acc[mt][nt]);
  }

  if (EPI == 4) {
    const int band = (n0 + wn) >> 10;
    const float* bp = band == 0 ? bias0 : (band == 1 ? bias1 : bias2);
#pragma unroll
    for (int nt = 0; nt < 4; nt++) {
      const int col = n0 + wn + nt * 16 + l16;
      const int cl = col & 1023;
      const float bv = bp[cl];
#pragma unroll
      for (int mt = 0; mt < 4; mt++) {
#pragma unroll
        for (int r = 0; r < 4; r++) {
          const int row = m0 + wm + mt * 16 + quad * 4 + r;
          const float v = acc[mt][nt][r] + bv;
          if (band == 0)
            ((unsigned short*)out)[(size_t)row * 1024 + cl] = f2b(v);
          else if (band == 1)
            outK[(size_t)row * 1024 + cl] = f2b(v);
          else
            outV[((size_t)((row >> 11) * 1024 + cl)) * 2048 + (row & 2047)] = f2b(v);
        }
      }
    }
  } else {
#pragma unroll
    for (int nt = 0; nt < 4; nt++) {
      const int col = n0 + wn + nt * 16 + l16;
      const float bv = (EPI == 3) ? 0.f : bias0[col];
#pragma unroll
      for (int mt = 0; mt < 4; mt++) {
#pragma unroll
        for (int r = 0; r < 4; r++) {
          const int row = m0 + wm + mt * 16 + quad * 4 + r;
          const size_t idx = (size_t)row * N + col;
          float v = acc[mt][nt][r] + bv;
          if (EPI == 2) {
            v = fmaxf(v, 0.f);
            ((unsigned short*)out)[idx] = f2b(v);
          } else {
            v += resid[idx];
            ((float*)out)[idx] = v;
          }
        }
      }
    }
  }
}

// ---------------------------------------------------------------------------
// Flash attention v4: QBLK=32 per wave (128 q-rows/block, grid (S/128, B*H)),
// single-buffered [64][64] K/V staged via global_load_lds with XOR chunk
// swizzle (rule 21). K-frags shared across the wave's two q-groups (4 MFMAs
// per K-read), V-frags shared (2 MFMAs per V-read), mask decode shared.
// Per-q LDS ~0.54x, VALU ~0.65x vs v3. LDS 34.8KB -> 4 blocks/CU; grid
// 1024 = exactly 4/CU. __launch_bounds__(256,4) pins VGPR <= 128.
// ---------------------------------------------------------------------------
__device__ __forceinline__ void attn_stage(const unsigned short* Kg,
                                           const unsigned short* Vg,
                                           unsigned short* Kd, unsigned short* Vd,
                                           int kt) {
  gload_lds16(Kg + (size_t)kt * 64 * D, Kd);
  gload_lds16(Kg + (size_t)kt * 64 * D + 8 * (size_t)D, Kd + 8 * 64);
  gload_lds16(Vg + (size_t)kt * 64, Vd);
  gload_lds16(Vg + (size_t)kt * 64 + 8 * (size_t)S, Vd + 8 * 64);
}

__global__ __launch_bounds__(256, 4) void attn_kernel(unsigned short* __restrict__ Q,
                                                      const unsigned short* __restrict__ Kb,
                                                      const unsigned short* __restrict__ VT,
                                                      const int* __restrict__ mask) {
  __shared__ __align__(16) unsigned short Ks[64 * 64];
  __shared__ __align__(16) unsigned short Vs[64 * 64];
  constexpr int PPAD = 72;
  __shared__ __align__(16) unsigned short Pb[8][16 * PPAD];  // [wave*2+qh]

  const int tid = threadIdx.x, lane = tid & 63, wave = tid >> 6;
  const int quad = lane >> 4, l16 = lane & 15;
  const int q0 = blockIdx.x * 128;
  const int b = blockIdx.y >> 4, h = blockIdx.y & 15;

  // staging: lane covers row (lane>>3) of an 8-row group, 16B chunk (lane&7);
  // global chunk pre-swizzled so LDS[r][c] holds logical chunk c^(r&7)
  const int sr = lane >> 3;
  const int sc8 = ((lane & 7) ^ sr) * 8;
  const unsigned short* Kg = Kb + ((size_t)b * S + wave * 16 + sr) * D + h * 64 + sc8;
  const unsigned short* Vg = VT + ((size_t)blockIdx.y * 64 + wave * 16 + sr) * S + sc8;
  unsigned short* Kd = &Ks[(wave * 16) * 64];
  unsigned short* Vd = &Vs[(wave * 16) * 64];

  // Q fragments: wave owns rows [q0+wave*32, +31], two q-groups of 16
  short8 qf[2][2];
#pragma unroll
  for (int qh = 0; qh < 2; qh++) {
    const unsigned short* qp =
        &Q[((size_t)b * S + q0 + wave * 32 + qh * 16 + l16) * D + h * 64 + quad * 8];
    qf[qh][0] = *(const short8*)qp;
    qf[qh][1] = *(const short8*)(qp + 32);
  }

  float l_acc[2] = {0.f, 0.f};
  f32x4 o_acc[2][4];
#pragma unroll
  for (int qh = 0; qh < 2; qh++)
#pragma unroll
    for (int t = 0; t < 4; t++) o_acc[qh][t] = {0.f, 0.f, 0.f, 0.f};

  // swizzled read chunk offsets (r&7 = l16&7 for frag rows)
  const int xr = l16 & 7;
  const int c0 = (quad ^ xr) * 8;
  const int c1 = ((quad + 4) ^ xr) * 8;

  for (int kt = 0; kt < S / 64; kt++) {
    const int k0 = kt * 64;
    BAR;  // all waves' reads of previous tile complete
    attn_stage(Kg, Vg, Kd, Vd, kt);
    VMC0;
    SB0;
    BAR;  // staged data visible to all waves

    // S^T = K Q^T for BOTH q-groups: each kf pair feeds 4 MFMAs
    f32x4 sc4[2][4];
#pragma unroll
    for (int qh = 0; qh < 2; qh++)
#pragma unroll
      for (int nt = 0; nt < 4; nt++) sc4[qh][nt] = {0.f, 0.f, 0.f, 0.f};
    PRIO1;
#pragma unroll
    for (int nt = 0; nt < 4; nt++) {
      short8 kf0 = *(const short8*)&Ks[(nt * 16 + l16) * 64 + c0];
      short8 kf1 = *(const short8*)&Ks[(nt * 16 + l16) * 64 + c1];
      sc4[0][nt] = mfma16(kf0, qf[0][0], sc4[0][nt]);
      sc4[0][nt] = mfma16(kf1, qf[0][1], sc4[0][nt]);
      sc4[1][nt] = mfma16(kf0, qf[1][0], sc4[1][nt]);
      sc4[1][nt] = mfma16(kf1, qf[1][1], sc4[1][nt]);
    }
    PRIO0;

    // softmax: mask decode shared across q-groups; cvt_pk pack, b64 writes
#pragma unroll
    for (int nt = 0; nt < 4; nt++) {
      const int4 mv = *(const int4*)&mask[b * S + k0 + nt * 16 + quad * 4];
      const float m0f = mv.x ? -12.f : -42.f;
      const float m1f = mv.y ? -12.f : -42.f;
      const float m2f = mv.z ? -12.f : -42.f;
      const float m3f = mv.w ? -12.f : -42.f;
#pragma unroll
      for (int qh = 0; qh < 2; qh++) {
        const float p0 = __expf(fmaf(sc4[qh][nt][0], 0.125f, m0f));
        const float p1 = __expf(fmaf(sc4[qh][nt][1], 0.125f, m1f));
        const float p2 = __expf(fmaf(sc4[qh][nt][2], 0.125f, m2f));
        const float p3 = __expf(fmaf(sc4[qh][nt][3], 0.125f, m3f));
        l_acc[qh] += (p0 + p1) + (p2 + p3);
        uint2 pw;
        pw.x = cvtpk_bf16(p0, p1);
        pw.y = cvtpk_bf16(p2, p3);
        *(uint2*)&Pb[wave * 2 + qh][l16 * PPAD + nt * 16 + quad * 4] = pw;
      }
    }

    // P @ V: vf pair shared across q-groups (2 MFMAs per V-read)
    short8 pf[2][2];
#pragma unroll
    for (int qh = 0; qh < 2; qh++) {
      pf[qh][0] = *(const short8*)&Pb[wave * 2 + qh][l16 * PPAD + quad * 8];
      pf[qh][1] = *(const short8*)&Pb[wave * 2 + qh][l16 * PPAD + 32 + quad * 8];
    }
    PRIO1;
#pragma unroll
    for (int nt = 0; nt < 4; nt++) {
      short8 vf0 = *(const short8*)&Vs[(nt * 16 + l16) * 64 + c0];
      short8 vf1 = *(const short8*)&Vs[(nt * 16 + l16) * 64 + c1];
      o_acc[0][nt] = mfma16(pf[0][0], vf0, o_acc[0][nt]);
      o_acc[0][nt] = mfma16(pf[0][1], vf1, o_acc[0][nt]);
      o_acc[1][nt] = mfma16(pf[1][0], vf0, o_acc[1][nt]);
      o_acc[1][nt] = mfma16(pf[1][1], vf1, o_acc[1][nt]);
    }
    PRIO0;
  }

  // l: sum across quads; normalize + store per q-group
#pragma unroll
  for (int qh = 0; qh < 2; qh++) {
    float la = l_acc[qh];
    la += __shfl_xor(la, 16);
    la += __shfl_xor(la, 32);
#pragma unroll
    for (int r = 0; r < 4; r++) {
      const float lr = __shfl(la, quad * 4 + r);
      const float inv = 1.f / lr;
      const int q = q0 + wave * 32 + qh * 16 + quad * 4 + r;
#pragma unroll
      for (int nt = 0; nt < 4; nt++) {
        const int dk = nt * 16 + l16;
        Q[((size_t)b * S + q) * D + h * 64 + dk] = f2b(o_acc[qh][nt][r] * inv);
      }
    }
  }
}

// ---------------------------------------------------------------------------
// FALLBACK path (ws < 89MB): round-5 kernels
// ---------------------------------------------------------------------------
__global__ __launch_bounds__(256) void stats_kernel(const float* __restrict__ x,
                                                    float2* __restrict__ st) {
  const int row = blockIdx.x, tid = threadIdx.x;
  const size_t base = (size_t)row * D;
  float s = 0.f, sq = 0.f;
#pragma unroll
  for (int i = 0; i < 4; i++) {
    const float v = x[base + tid + i * 256];
    s += v;
    sq += v * v;
  }
#pragma unroll
  for (int o = 32; o > 0; o >>= 1) {
    s += __shfl_xor(s, o);
    sq += __shfl_xor(sq, o);
  }
  __shared__ __align__(16) float rs[4], rq[4];
  const int wave = tid >> 6, lane = tid & 63;
  if (lane == 0) {
    rs[wave] = s;
    rq[wave] = sq;
  }
  __syncthreads();
  if (tid == 0) {
    const float S1 = rs[0] + rs[1] + rs[2] + rs[3];
    const float S2 = rq[0] + rq[1] + rq[2] + rq[3];
    const float mean = S1 * (1.f / 1024.f);
    const float var = fmaxf(0.f, (S2 - 1024.f * mean * mean) * (1.f / 1023.f));
    const float rstd = 1.f / (sqrtf(var) + 1e-6f);
    st[row] = make_float2(mean, rstd);
  }
}

template <int EPI, int NORM, int AF32, int OUTF32>
__global__ __launch_bounds__(256) void gemm_bt(
    const void* __restrict__ Ap, const float* __restrict__ W,
    const float* __restrict__ bias, const float* __restrict__ resid,
    void* __restrict__ outp, const float2* __restrict__ stats,
    const float* __restrict__ alpha_p, const float* __restrict__ beta_p,
    int M, int N, int K, int ldw) {
  __shared__ __align__(16) unsigned short As[128 * 32];
  __shared__ __align__(16) unsigned short Bs[128 * 32];
  const int tid = threadIdx.x;
  const int lane = tid & 63, wave = tid >> 6;
  const int quad = lane >> 4, l16 = lane & 15;
  const int m0 = blockIdx.y * 128, n0 = blockIdx.x * 128;
  const int wm = (wave >> 1) * 64, wn = (wave & 1) * 64;

  float alpha = 0.f, beta = 0.f;
  if (NORM) {
    alpha = alpha_p[0];
    beta = beta_p[0];
  }

  f32x4 acc[4][4];
#pragma unroll
  for (int i = 0; i < 4; i++)
#pragma unroll
    for (int j = 0; j < 4; j++) acc[i][j] = {0.f, 0.f, 0.f, 0.f};

  const int rA = tid >> 2;
  const int kc = (tid & 3) * 8;

  for (int k0 = 0; k0 < K; k0 += 32) {
    ushort8 av[2], bv8[2];
#pragma unroll
    for (int i = 0; i < 2; i++) {
      const int row = i * 64 + rA;
      if (AF32) {
        const float* ap = (const float*)Ap + (size_t)(m0 + row) * K + k0 + kc;
        f32x4 a0 = *(const f32x4*)ap;
        f32x4 a1 = *(const f32x4*)(ap + 4);
        if (NORM) {
          const float2 st = stats[m0 + row];
#pragma unroll
          for (int j = 0; j < 4; j++) {
            a0[j] = alpha * (a0[j] - st.x) * st.y + beta;
            a1[j] = alpha * (a1[j] - st.x) * st.y + beta;
          }
        }
#pragma unroll
        for (int j = 0; j < 4; j++) {
          av[i][j] = f2b(a0[j]);
          av[i][j + 4] = f2b(a1[j]);
        }
      } else {
        av[i] = *(const ushort8*)((const unsigned short*)Ap +
                                  (size_t)(m0 + row) * K + k0 + kc);
      }
      const float* wp = W + (size_t)(n0 + row) * ldw + k0 + kc;
      f32x4 w0 = *(const f32x4*)wp;
      f32x4 w1 = *(const f32x4*)(wp + 4);
#pragma unroll
      for (int j = 0; j < 4; j++) {
        bv8[i][j] = f2b(w0[j]);
        bv8[i][j + 4] = f2b(w1[j]);
      }
    }
    __syncthreads();
#pragma unroll
    for (int i = 0; i < 2; i++) {
      const int row = i * 64 + rA;
      *(ushort8*)&As[row * 32 + kc] = av[i];
      *(ushort8*)&Bs[row * 32 + kc] = bv8[i];
    }
    __syncthreads();
    short8 af[4], bf[4];
#pragma unroll
    for (int t = 0; t < 4; t++) {
      af[t] = *(const short8*)&As[(wm + t * 16 + l16) * 32 + quad * 8];
      bf[t] = *(const short8*)&Bs[(wn + t * 16 + l16) * 32 + quad * 8];
    }
#pragma unroll
    for (int mt = 0; mt < 4; mt++)
#pragma unroll
      for (int nt = 0; nt < 4; nt++) acc[mt][nt] = mfma16(af[mt], bf[nt], acc[mt][nt]);
  }

#pragma unroll
  for (int nt = 0; nt < 4; nt++) {
    const int col = n0 + wn + nt * 16 + l16;
    const float bv = (EPI == 3) ? 0.f : bias[col];
#pragma unroll
    for (int mt = 0; mt < 4; mt++) {
#pragma unroll
      for (int r = 0; r < 4; r++) {
        const int row = m0 + wm + mt * 16 + quad * 4 + r;
        float v = acc[mt][nt][r] + bv;
        if (EPI == 2) v = fmaxf(v, 0.f);
        if (EPI == 4) {
          const size_t vtidx =
              ((size_t)((row >> 11) * 1024 + col)) * 2048 + (row & 2047);
          ((unsigned short*)outp)[vtidx] = f2b(v);
        } else {
          const size_t idx = (size_t)row * N + col;
          if (EPI == 1 || EPI == 3) v += resid[idx];
          if (OUTF32)
            ((float*)outp)[idx] = v;
          else
            ((unsigned short*)outp)[idx] = f2b(v);
        }
      }
    }
  }
}

// ---------------------------------------------------------------------------
extern "C" void kernel_launch(void* const* d_in, const int* in_sizes, int n_in,
                              void* d_out, int out_size, void* d_ws, size_t ws_size,
                              hipStream_t stream) {
  (void)in_sizes; (void)n_in; (void)out_size;
  const float* x  = (const float*)d_in[0];
  const int* mask = (const int*)d_in[1];
  const float* wq = (const float*)d_in[2];
  const float* bq = (const float*)d_in[3];
  const float* wk = (const float*)d_in[4];
  const float* bk = (const float*)d_in[5];
  const float* wv = (const float*)d_in[6];
  const float* bv = (const float*)d_in[7];
  const float* wo = (const float*)d_in[8];
  const float* bo = (const float*)d_in[9];
  const float* w1 = (const float*)d_in[10];
  const float* b1 = (const float*)d_in[11];
  const float* w2 = (const float*)d_in[12];
  const float* b2 = (const float*)d_in[13];
  const float* a1 = (const float*)d_in[14];
  const float* c1 = (const float*)d_in[15];
  const float* a2 = (const float*)d_in[16];
  const float* c2 = (const float*)d_in[17];

  char* ws = (char*)d_ws;
  const size_t MB = 1 << 20;
  const int M = B * S;  // 8192
  dim3 blk(256);
  dim3 gAttn(S / 128, B * H);  // (16, 64)

  if (ws_size >= 89 * MB) {
    const int tier3 = (ws_size >= 152 * MB);
    const int tier2 = (ws_size >= 121 * MB);
    unsigned short* wqkv_b = (unsigned short*)(ws + 0);        // 6 MB
    unsigned short* wo_b   = (unsigned short*)(ws + 6 * MB);   // 2 MB
    unsigned short* w1_b   = (unsigned short*)(ws + 8 * MB);   // 8 MB
    unsigned short* w2_b   = (unsigned short*)(ws + 16 * MB);  // 8 MB
    unsigned short* ln1x   = (unsigned short*)(ws + 25 * MB);  // 16 MB
    unsigned short* q      = (unsigned short*)(ws + 41 * MB);  // 16 MB
    unsigned short* kk     = (unsigned short*)(ws + 57 * MB);  // 16 MB
    unsigned short* vt     = (unsigned short*)(ws + 73 * MB);  // 16 MB
    float*          hbuf   = (float*)(ws + 57 * MB);           // 32 MB (over kk+vt)
    unsigned short* ln2x   = (unsigned short*)(ws + 25 * MB);  // over ln1x
    unsigned short* ffn1q  = (unsigned short*)(ws + 41 * MB);  // over q (tier1)
    unsigned short* ffn1h  = (unsigned short*)(ws + 89 * MB);  // 32 MB (tier2)
    unsigned short* ffn1f  = (unsigned short*)(ws + 89 * MB);  // 64 MB (tier3)
    float* outb = (float*)d_out;

    // weights -> bf16, one batched dispatch
    CvtArgs ca;
    ca.s[0] = wq; ca.d[0] = wqkv_b;            ca.n[0] = 1048576;
    ca.s[1] = wk; ca.d[1] = wqkv_b + 1048576;  ca.n[1] = 1048576;
    ca.s[2] = wv; ca.d[2] = wqkv_b + 2097152;  ca.n[2] = 1048576;
    ca.s[3] = wo; ca.d[3] = wo_b;              ca.n[3] = 1048576;
    ca.s[4] = w1; ca.d[4] = w1_b;              ca.n[4] = 4194304;
    ca.s[5] = w2; ca.d[5] = w2_b;              ca.n[5] = 4194304;
    convert6<<<dim3(4096, 6), blk, 0, stream>>>(ca);

    ln_fused<<<M, blk, 0, stream>>>(x, a1, c1, ln1x);
    gemm_bb<4><<<dim3(24, 64), blk, 0, stream>>>(ln1x, wqkv_b, bq, bk, bv, nullptr,
                                                 q, kk, vt, M, 3072, D, D);
    attn_kernel<<<gAttn, blk, 0, stream>>>(q, kk, vt, mask);
    gemm_bb<1><<<dim3(8, 64), blk, 0, stream>>>(q, wo_b, bo, nullptr, nullptr, x,
                                                hbuf, nullptr, nullptr, M, D, D, D);
    ln_fused<<<M, blk, 0, stream>>>(hbuf, a2, c2, ln2x);

    if (tier3) {
      // one full FFN1 (N=4096) + one full-K FFN2 (K=4096)
      gemm_bb<2><<<dim3(32, 64), blk, 0, stream>>>(ln2x, w1_b, b1, nullptr, nullptr,
                                                   nullptr, ffn1f, nullptr, nullptr,
                                                   M, DFF, D, D);
      gemm_bb<1><<<dim3(8, 64), blk, 0, stream>>>(ffn1f, w2_b, b2, nullptr, nullptr,
                                                  hbuf, outb, nullptr, nullptr,
                                                  M, D, DFF, DFF);
    } else if (tier2) {
      gemm_bb<2><<<dim3(16, 64), blk, 0, stream>>>(ln2x, w1_b, b1, nullptr, nullptr,
                                                   nullptr, ffn1h, nullptr, nullptr,
                                                   M, 2048, D, D);
      gemm_bb<1><<<dim3(8, 64), blk, 0, stream>>>(ffn1h, w2_b, b2, nullptr, nullptr,
                                                  hbuf, outb, nullptr, nullptr,
                                                  M, D, 2048, DFF);
      gemm_bb<2><<<dim3(16, 64), blk, 0, stream>>>(ln2x, w1_b + (size_t)2048 * D,
                                                   b1 + 2048, nullptr, nullptr, nullptr,
                                                   ffn1h, nullptr, nullptr, M, 2048, D, D);
      gemm_bb<3><<<dim3(8, 64), blk, 0, stream>>>(ffn1h, w2_b + 2048, nullptr, nullptr,
                                                  nullptr, outb, outb, nullptr, nullptr,
                                                  M, D, 2048, DFF);
    } else {
      for (int i = 0; i < 4; i++) {
        gemm_bb<2><<<dim3(8, 64), blk, 0, stream>>>(ln2x, w1_b + (size_t)i * 1024 * D,
                                                    b1 + i * 1024, nullptr, nullptr,
                                                    nullptr, ffn1q, nullptr, nullptr,
                                                    M, 1024, D, D);
        if (i == 0)
          gemm_bb<1><<<dim3(8, 64), blk, 0, stream>>>(ffn1q, w2_b + i * 1024, b2, nullptr,
                                                      nullptr, hbuf, outb, nullptr, nullptr,
                                                      M, D, 1024, DFF);
        else
          gemm_bb<3><<<dim3(8, 64), blk, 0, stream>>>(ffn1q, w2_b + i * 1024, nullptr,
                                                      nullptr, nullptr, outb, outb, nullptr,
                                                      nullptr, M, D, 1024, DFF);
      }
    }
  } else {
    // fallback (round-5 structure, 49 MB peak)
    float2* stats1 = (float2*)(ws + 0);
    float2* stats2 = (float2*)(ws + 128 * 1024);
    unsigned short* q    = (unsigned short*)(ws + 1 * MB);
    unsigned short* kk   = (unsigned short*)(ws + 17 * MB);
    unsigned short* vt   = (unsigned short*)(ws + 33 * MB);
    float*          hbuf = (float*)(ws + 17 * MB);
    unsigned short* ffn1 = (unsigned short*)(ws + 1 * MB);
    float* outb = (float*)d_out;
    dim3 gD(D / 128, M / 128);

    stats_kernel<<<M, blk, 0, stream>>>(x, stats1);
    gemm_bt<0, 1, 1, 0><<<gD, blk, 0, stream>>>(x, wq, bq, nullptr, q, stats1, a1, c1, M, D, D, D);
    gemm_bt<0, 1, 1, 0><<<gD, blk, 0, stream>>>(x, wk, bk, nullptr, kk, stats1, a1, c1, M, D, D, D);
    gemm_bt<4, 1, 1, 0><<<gD, blk, 0, stream>>>(x, wv, bv, nullptr, vt, stats1, a1, c1, M, D, D, D);
    attn_kernel<<<gAttn, blk, 0, stream>>>(q, kk, vt, mask);
    gemm_bt<1, 0, 0, 1><<<gD, blk, 0, stream>>>(q, wo, bo, x, hbuf, nullptr, nullptr, nullptr, M, D, D, D);
    stats_kernel<<<M, blk, 0, stream>>>(hbuf, stats2);
    for (int i = 0; i < 4; i++) {
      gemm_bt<2, 1, 1, 0><<<gD, blk, 0, stream>>>(hbuf, w1 + (size_t)i * 1024 * D,
                                                  b1 + i * 1024, nullptr, ffn1, stats2,
                                                  a2, c2, M, 1024, D, D);
      if (i == 0)
        gemm_bt<1, 0, 0, 1><<<gD, blk, 0, stream>>>(ffn1, w2 + i * 1024, b2, hbuf, outb,
                                                    nullptr, nullptr, nullptr, M, D, 1024, DFF);
      else
        gemm_bt<3, 0, 0, 1><<<gD, blk, 0, stream>>>(ffn1, w2 + i * 1024, nullptr, outb, outb,
                                                    nullptr, nullptr, nullptr, M, D, 1024, DFF);
    }
  }
}

// Round 5
// 548.749 us; speedup vs baseline: 1.1592x; 1.0862x over previous
//
#include <hip/hip_runtime.h>
#include <math.h>

static constexpr int B  = 4;
static constexpr int S  = 2048;
static constexpr int D  = 1024;
static constexpr int H  = 16;
static constexpr int DFF = 4096;

typedef __attribute__((ext_vector_type(8))) short short8;
typedef __attribute__((ext_vector_type(8))) unsigned short ushort8;
typedef __attribute__((ext_vector_type(4))) unsigned short ushort4v;
typedef __attribute__((ext_vector_type(4))) float f32x4;

__device__ __forceinline__ float b2f(unsigned short u) {
  unsigned int x = ((unsigned int)u) << 16;
  float f;
  __builtin_memcpy(&f, &x, 4);
  return f;
}
__device__ __forceinline__ unsigned short f2b(float f) {
  unsigned int x;
  __builtin_memcpy(&x, &f, 4);
  x += 0x7fffu + ((x >> 16) & 1u);  // round-to-nearest-even
  return (unsigned short)(x >> 16);
}

// packed f32x2 -> bf16x2 (RNE), single VALU op (no builtin on gfx950)
__device__ __forceinline__ unsigned int cvtpk_bf16(float lo, float hi) {
  unsigned int r;
  asm("v_cvt_pk_bf16_f32 %0, %1, %2" : "=v"(r) : "v"(lo), "v"(hi));
  return r;
}

__device__ __forceinline__ f32x4 mfma16(short8 a, short8 b, f32x4 c) {
  return __builtin_amdgcn_mfma_f32_16x16x32_bf16(a, b, c, 0, 0, 0);
}

// global -> LDS direct copy, 16B per lane (wave-uniform base + lane*16).
__device__ __forceinline__ void gload_lds16(const void* gsrc, void* ldst) {
  __builtin_amdgcn_global_load_lds(
      (__attribute__((address_space(1))) void*)(uintptr_t)gsrc,
      (__attribute__((address_space(3))) void*)ldst, 16, 0, 0);
}

#define VMC0 asm volatile("s_waitcnt vmcnt(0)" ::: "memory")
#define SB0  __builtin_amdgcn_sched_barrier(0)
#define BAR  __builtin_amdgcn_s_barrier()
#define PRIO1 __builtin_amdgcn_s_setprio(1)
#define PRIO0 __builtin_amdgcn_s_setprio(0)

// XCD-aware bijective block swizzle (requires nwg % 8 == 0): contiguous
// work-tile chunks per XCD -> shared A/W panels hit the same L2. [T1]
__device__ __forceinline__ int xcd_swz(int wg, int nwg) {
  if (!(nwg & 7)) wg = (wg & 7) * (nwg >> 3) + (wg >> 3);
  return wg;
}

// ---------------------------------------------------------------------------
// Batched f32 -> bf16 convert: 6 segments, grid (maxblocks, 6)
// ---------------------------------------------------------------------------
struct CvtArgs {
  const float* s[6];
  unsigned short* d[6];
  int n[6];
};
__global__ __launch_bounds__(256) void convert6(CvtArgs a) {
  const int seg = blockIdx.y;
  const int i = (blockIdx.x * 256 + threadIdx.x) * 4;
  if (i < a.n[seg]) {
    f32x4 v = *(const f32x4*)(a.s[seg] + i);
    ushort4v o;
#pragma unroll
    for (int j = 0; j < 4; j++) o[j] = f2b(v[j]);
    *(ushort4v*)(a.d[seg] + i) = o;
  }
}

// ---------------------------------------------------------------------------
// Fused LayerNorm (f32 in -> bf16 out): alpha*(x-mean)/(std+eps)+beta, ddof=1
// ---------------------------------------------------------------------------
__global__ __launch_bounds__(256) void ln_fused(const float* __restrict__ x,
                                                const float* __restrict__ ap,
                                                const float* __restrict__ cp,
                                                unsigned short* __restrict__ out) {
  const int row = blockIdx.x, tid = threadIdx.x;
  const size_t base = (size_t)row * D;
  float v[4];
  float s = 0.f, sq = 0.f;
#pragma unroll
  for (int i = 0; i < 4; i++) {
    v[i] = x[base + tid + i * 256];
    s += v[i];
    sq += v[i] * v[i];
  }
#pragma unroll
  for (int o = 32; o > 0; o >>= 1) {
    s += __shfl_xor(s, o);
    sq += __shfl_xor(sq, o);
  }
  __shared__ __align__(16) float rs[4], rq[4];
  const int wave = tid >> 6, lane = tid & 63;
  if (lane == 0) {
    rs[wave] = s;
    rq[wave] = sq;
  }
  __syncthreads();
  const float S1 = rs[0] + rs[1] + rs[2] + rs[3];
  const float S2 = rq[0] + rq[1] + rq[2] + rq[3];
  const float mean = S1 * (1.f / 1024.f);
  const float var = fmaxf(0.f, (S2 - 1024.f * mean * mean) * (1.f / 1023.f));
  const float rstd = 1.f / (sqrtf(var) + 1e-6f);
  const float alpha = ap[0], beta = cp[0];
#pragma unroll
  for (int i = 0; i < 4; i++)
    out[base + tid + i * 256] = f2b(alpha * (v[i] - mean) * rstd + beta);
}

// ---------------------------------------------------------------------------
// Pure-bf16 GEMM (m97 structure + XCD swizzle): C = A @ W^T.
// 128x128 tile, BK=32, 4 waves, 4x4 MFMA frags.
// EPI 1: f32 out = acc + bias0 + f32 resid
// EPI 2: bf16 out = relu(acc + bias0)
// EPI 3: f32 out = acc + f32 resid              (no bias)
// EPI 4: QKV fused: col band 0 -> out (bf16), 1 -> outK (bf16),
//        2 -> outV transposed [(row>>11)*1024+cl][row&2047] (bf16)
// ---------------------------------------------------------------------------
template <int EPI>
__global__ __launch_bounds__(256) void gemm_bb(
    const unsigned short* __restrict__ A, const unsigned short* __restrict__ W,
    const float* __restrict__ bias0, const float* __restrict__ bias1,
    const float* __restrict__ bias2, const float* __restrict__ resid,
    void* __restrict__ out, unsigned short* __restrict__ outK,
    unsigned short* __restrict__ outV, int M, int N, int K, int ldw) {
  __shared__ __align__(16) unsigned short As[128 * 32];
  __shared__ __align__(16) unsigned short Bs[128 * 32];
  const int tid = threadIdx.x;
  const int lane = tid & 63, wave = tid >> 6;
  const int quad = lane >> 4, l16 = lane & 15;
  const int nbx = gridDim.x;
  const int wg = xcd_swz(blockIdx.y * nbx + blockIdx.x, nbx * gridDim.y);
  const int m0 = (wg / nbx) * 128, n0 = (wg % nbx) * 128;
  const int wm = (wave >> 1) * 64, wn = (wave & 1) * 64;

  f32x4 acc[4][4];
#pragma unroll
  for (int i = 0; i < 4; i++)
#pragma unroll
    for (int j = 0; j < 4; j++) acc[i][j] = {0.f, 0.f, 0.f, 0.f};

  const int rA = tid >> 2;       // 0..63 row within half-tile
  const int kc = (tid & 3) * 8;  // 8-elem (16B) chunk

  for (int k0 = 0; k0 < K; k0 += 32) {
    __syncthreads();
#pragma unroll
    for (int i = 0; i < 2; i++) {
      const int row = i * 64 + rA;
      gload_lds16(&A[(size_t)(m0 + row) * K + k0 + kc], &As[(i * 256 + wave * 64) * 8]);
      gload_lds16(&W[(size_t)(n0 + row) * ldw + k0 + kc], &Bs[(i * 256 + wave * 64) * 8]);
    }
    __syncthreads();
    short8 af[4], bf[4];
#pragma unroll
    for (int t = 0; t < 4; t++) {
      af[t] = *(const short8*)&As[(wm + t * 16 + l16) * 32 + quad * 8];
      bf[t] = *(const short8*)&Bs[(wn + t * 16 + l16) * 32 + quad * 8];
    }
#pragma unroll
    for (int mt = 0; mt < 4; mt++)
#pragma unroll
      for (int nt = 0; nt < 4; nt++) acc[mt][nt] = mfma16(af[mt], bf[nt], acc[mt][nt]);
  }

  if (EPI == 4) {
    const int band = (n0 + wn) >> 10;
    const float* bp = band == 0 ? bias0 : (band == 1 ? bias1 : bias2);
#pragma unroll
    for (int nt = 0; nt < 4; nt++) {
      const int col = n0 + wn + nt * 16 + l16;
      const int cl = col & 1023;
      const float bv = bp[cl];
#pragma unroll
      for (int mt = 0; mt < 4; mt++) {
#pragma unroll
        for (int r = 0; r < 4; r++) {
          const int row = m0 + wm + mt * 16 + quad * 4 + r;
          const float v = acc[mt][nt][r] + bv;
          if (band == 0)
            ((unsigned short*)out)[(size_t)row * 1024 + cl] = f2b(v);
          else if (band == 1)
            outK[(size_t)row * 1024 + cl] = f2b(v);
          else
            outV[((size_t)((row >> 11) * 1024 + cl)) * 2048 + (row & 2047)] = f2b(v);
        }
      }
    }
  } else {
#pragma unroll
    for (int nt = 0; nt < 4; nt++) {
      const int col = n0 + wn + nt * 16 + l16;
      const float bv = (EPI == 3) ? 0.f : bias0[col];
#pragma unroll
      for (int mt = 0; mt < 4; mt++) {
#pragma unroll
        for (int r = 0; r < 4; r++) {
          const int row = m0 + wm + mt * 16 + quad * 4 + r;
          const size_t idx = (size_t)row * N + col;
          float v = acc[mt][nt][r] + bv;
          if (EPI == 2) {
            v = fmaxf(v, 0.f);
            ((unsigned short*)out)[idx] = f2b(v);
          } else {
            v += resid[idx];
            ((float*)out)[idx] = v;
          }
        }
      }
    }
  }
}

// ---------------------------------------------------------------------------
// BK=64 GEMM for the grid-limited N=1024 GEMMs (AO, FFN2; grid (8,64) = 2
// blocks/CU, so LDS 32KB is free). 32 MFMA per barrier-pair (2x gemm_bb),
// XOR-chunk-swizzled LDS (128B row stride would be 32-way conflict): stage
// with pre-swizzled global source + linear gload_lds dest, read with
// c = (kh*4+quad)^(l16&7) — same involution as attn v3/v4. + XCD swizzle.
// EPI 1: f32 out = acc + bias0 + resid;  EPI 3: f32 out = acc + resid.
// Requires K % 64 == 0.
// ---------------------------------------------------------------------------
template <int EPI>
__global__ __launch_bounds__(256) void gemm_bb64(
    const unsigned short* __restrict__ A, const unsigned short* __restrict__ W,
    const float* __restrict__ bias0, const float* __restrict__ resid,
    float* __restrict__ out, int M, int N, int K, int ldw) {
  __shared__ __align__(16) unsigned short As[128 * 64];
  __shared__ __align__(16) unsigned short Bs[128 * 64];
  const int tid = threadIdx.x;
  const int lane = tid & 63, wave = tid >> 6;
  const int quad = lane >> 4, l16 = lane & 15;
  const int nbx = gridDim.x;
  const int wg = xcd_swz(blockIdx.y * nbx + blockIdx.x, nbx * gridDim.y);
  const int m0 = (wg / nbx) * 128, n0 = (wg % nbx) * 128;
  const int wm = (wave >> 1) * 64, wn = (wave & 1) * 64;

  f32x4 acc[4][4];
#pragma unroll
  for (int i = 0; i < 4; i++)
#pragma unroll
    for (int j = 0; j < 4; j++) acc[i][j] = {0.f, 0.f, 0.f, 0.f};

  // staging: lane -> row group sr = lane>>3, chunk pre-swizzled
  const int sr = lane >> 3;
  const int sc = ((lane & 7) ^ sr) * 8;
  // frag read: swizzled chunk offsets (row&7 == l16&7 for frag rows)
  const int xr = l16 & 7;
  const int c0 = (quad ^ xr) * 8;        // kh = 0
  const int c1 = ((4 + quad) ^ xr) * 8;  // kh = 1

  for (int k0 = 0; k0 < K; k0 += 64) {
    __syncthreads();
#pragma unroll
    for (int j = 0; j < 4; j++) {
      const int row = j * 32 + wave * 8 + sr;
      gload_lds16(&A[(size_t)(m0 + row) * K + k0 + sc], &As[(j * 32 + wave * 8) * 64]);
      gload_lds16(&W[(size_t)(n0 + row) * ldw + k0 + sc], &Bs[(j * 32 + wave * 8) * 64]);
    }
    __syncthreads();
    short8 af[4][2], bf[4][2];
#pragma unroll
    for (int t = 0; t < 4; t++) {
      af[t][0] = *(const short8*)&As[(wm + t * 16 + l16) * 64 + c0];
      af[t][1] = *(const short8*)&As[(wm + t * 16 + l16) * 64 + c1];
      bf[t][0] = *(const short8*)&Bs[(wn + t * 16 + l16) * 64 + c0];
      bf[t][1] = *(const short8*)&Bs[(wn + t * 16 + l16) * 64 + c1];
    }
#pragma unroll
    for (int mt = 0; mt < 4; mt++)
#pragma unroll
      for (int nt = 0; nt < 4; nt++) {
        acc[mt][nt] = mfma16(af[mt][0], bf[nt][0], acc[mt][nt]);
        acc[mt][nt] = mfma16(af[mt][1], bf[nt][1], acc[mt][nt]);
      }
  }

#pragma unroll
  for (int nt = 0; nt < 4; nt++) {
    const int col = n0 + wn + nt * 16 + l16;
    const float bv = (EPI == 3) ? 0.f : bias0[col];
#pragma unroll
    for (int mt = 0; mt < 4; mt++) {
#pragma unroll
      for (int r = 0; r < 4; r++) {
        const int row = m0 + wm + mt * 16 + quad * 4 + r;
        const size_t idx = (size_t)row * N + col;
        out[idx] = acc[mt][nt][r] + bv + resid[idx];
      }
    }
  }
}

// ---------------------------------------------------------------------------
// Flash attention v4: QBLK=32 per wave (128 q-rows/block, grid (S/128, B*H)),
// single-buffered [64][64] K/V staged via global_load_lds with XOR chunk
// swizzle (rule 21). K-frags shared across the wave's two q-groups (4 MFMAs
// per K-read), V-frags shared (2 MFMAs per V-read), mask decode shared.
// ---------------------------------------------------------------------------
__device__ __forceinline__ void attn_stage(const unsigned short* Kg,
                                           const unsigned short* Vg,
                                           unsigned short* Kd, unsigned short* Vd,
                                           int kt) {
  gload_lds16(Kg + (size_t)kt * 64 * D, Kd);
  gload_lds16(Kg + (size_t)kt * 64 * D + 8 * (size_t)D, Kd + 8 * 64);
  gload_lds16(Vg + (size_t)kt * 64, Vd);
  gload_lds16(Vg + (size_t)kt * 64 + 8 * (size_t)S, Vd + 8 * 64);
}

__global__ __launch_bounds__(256, 4) void attn_kernel(unsigned short* __restrict__ Q,
                                                      const unsigned short* __restrict__ Kb,
                                                      const unsigned short* __restrict__ VT,
                                                      const int* __restrict__ mask) {
  __shared__ __align__(16) unsigned short Ks[64 * 64];
  __shared__ __align__(16) unsigned short Vs[64 * 64];
  constexpr int PPAD = 72;
  __shared__ __align__(16) unsigned short Pb[8][16 * PPAD];  // [wave*2+qh]

  const int tid = threadIdx.x, lane = tid & 63, wave = tid >> 6;
  const int quad = lane >> 4, l16 = lane & 15;
  const int q0 = blockIdx.x * 128;
  const int b = blockIdx.y >> 4, h = blockIdx.y & 15;

  const int sr = lane >> 3;
  const int sc8 = ((lane & 7) ^ sr) * 8;
  const unsigned short* Kg = Kb + ((size_t)b * S + wave * 16 + sr) * D + h * 64 + sc8;
  const unsigned short* Vg = VT + ((size_t)blockIdx.y * 64 + wave * 16 + sr) * S + sc8;
  unsigned short* Kd = &Ks[(wave * 16) * 64];
  unsigned short* Vd = &Vs[(wave * 16) * 64];

  short8 qf[2][2];
#pragma unroll
  for (int qh = 0; qh < 2; qh++) {
    const unsigned short* qp =
        &Q[((size_t)b * S + q0 + wave * 32 + qh * 16 + l16) * D + h * 64 + quad * 8];
    qf[qh][0] = *(const short8*)qp;
    qf[qh][1] = *(const short8*)(qp + 32);
  }

  float l_acc[2] = {0.f, 0.f};
  f32x4 o_acc[2][4];
#pragma unroll
  for (int qh = 0; qh < 2; qh++)
#pragma unroll
    for (int t = 0; t < 4; t++) o_acc[qh][t] = {0.f, 0.f, 0.f, 0.f};

  const int xr = l16 & 7;
  const int c0 = (quad ^ xr) * 8;
  const int c1 = ((quad + 4) ^ xr) * 8;

  for (int kt = 0; kt < S / 64; kt++) {
    const int k0 = kt * 64;
    BAR;  // all waves' reads of previous tile complete
    attn_stage(Kg, Vg, Kd, Vd, kt);
    VMC0;
    SB0;
    BAR;  // staged data visible to all waves

    // S^T = K Q^T for BOTH q-groups: each kf pair feeds 4 MFMAs
    f32x4 sc4[2][4];
#pragma unroll
    for (int qh = 0; qh < 2; qh++)
#pragma unroll
      for (int nt = 0; nt < 4; nt++) sc4[qh][nt] = {0.f, 0.f, 0.f, 0.f};
    PRIO1;
#pragma unroll
    for (int nt = 0; nt < 4; nt++) {
      short8 kf0 = *(const short8*)&Ks[(nt * 16 + l16) * 64 + c0];
      short8 kf1 = *(const short8*)&Ks[(nt * 16 + l16) * 64 + c1];
      sc4[0][nt] = mfma16(kf0, qf[0][0], sc4[0][nt]);
      sc4[0][nt] = mfma16(kf1, qf[0][1], sc4[0][nt]);
      sc4[1][nt] = mfma16(kf0, qf[1][0], sc4[1][nt]);
      sc4[1][nt] = mfma16(kf1, qf[1][1], sc4[1][nt]);
    }
    PRIO0;

    // softmax: mask decode shared across q-groups; cvt_pk pack, b64 writes
#pragma unroll
    for (int nt = 0; nt < 4; nt++) {
      const int4 mv = *(const int4*)&mask[b * S + k0 + nt * 16 + quad * 4];
      const float m0f = mv.x ? -12.f : -42.f;
      const float m1f = mv.y ? -12.f : -42.f;
      const float m2f = mv.z ? -12.f : -42.f;
      const float m3f = mv.w ? -12.f : -42.f;
#pragma unroll
      for (int qh = 0; qh < 2; qh++) {
        const float p0 = __expf(fmaf(sc4[qh][nt][0], 0.125f, m0f));
        const float p1 = __expf(fmaf(sc4[qh][nt][1], 0.125f, m1f));
        const float p2 = __expf(fmaf(sc4[qh][nt][2], 0.125f, m2f));
        const float p3 = __expf(fmaf(sc4[qh][nt][3], 0.125f, m3f));
        l_acc[qh] += (p0 + p1) + (p2 + p3);
        uint2 pw;
        pw.x = cvtpk_bf16(p0, p1);
        pw.y = cvtpk_bf16(p2, p3);
        *(uint2*)&Pb[wave * 2 + qh][l16 * PPAD + nt * 16 + quad * 4] = pw;
      }
    }

    // P @ V: vf pair shared across q-groups (2 MFMAs per V-read)
    short8 pf[2][2];
#pragma unroll
    for (int qh = 0; qh < 2; qh++) {
      pf[qh][0] = *(const short8*)&Pb[wave * 2 + qh][l16 * PPAD + quad * 8];
      pf[qh][1] = *(const short8*)&Pb[wave * 2 + qh][l16 * PPAD + 32 + quad * 8];
    }
    PRIO1;
#pragma unroll
    for (int nt = 0; nt < 4; nt++) {
      short8 vf0 = *(const short8*)&Vs[(nt * 16 + l16) * 64 + c0];
      short8 vf1 = *(const short8*)&Vs[(nt * 16 + l16) * 64 + c1];
      o_acc[0][nt] = mfma16(pf[0][0], vf0, o_acc[0][nt]);
      o_acc[0][nt] = mfma16(pf[0][1], vf1, o_acc[0][nt]);
      o_acc[1][nt] = mfma16(pf[1][0], vf0, o_acc[1][nt]);
      o_acc[1][nt] = mfma16(pf[1][1], vf1, o_acc[1][nt]);
    }
    PRIO0;
  }

  // l: sum across quads; normalize + store per q-group
#pragma unroll
  for (int qh = 0; qh < 2; qh++) {
    float la = l_acc[qh];
    la += __shfl_xor(la, 16);
    la += __shfl_xor(la, 32);
#pragma unroll
    for (int r = 0; r < 4; r++) {
      const float lr = __shfl(la, quad * 4 + r);
      const float inv = 1.f / lr;
      const int q = q0 + wave * 32 + qh * 16 + quad * 4 + r;
#pragma unroll
      for (int nt = 0; nt < 4; nt++) {
        const int dk = nt * 16 + l16;
        Q[((size_t)b * S + q) * D + h * 64 + dk] = f2b(o_acc[qh][nt][r] * inv);
      }
    }
  }
}

// ---------------------------------------------------------------------------
// FALLBACK path (ws < 89MB): round-5 kernels
// ---------------------------------------------------------------------------
__global__ __launch_bounds__(256) void stats_kernel(const float* __restrict__ x,
                                                    float2* __restrict__ st) {
  const int row = blockIdx.x, tid = threadIdx.x;
  const size_t base = (size_t)row * D;
  float s = 0.f, sq = 0.f;
#pragma unroll
  for (int i = 0; i < 4; i++) {
    const float v = x[base + tid + i * 256];
    s += v;
    sq += v * v;
  }
#pragma unroll
  for (int o = 32; o > 0; o >>= 1) {
    s += __shfl_xor(s, o);
    sq += __shfl_xor(sq, o);
  }
  __shared__ __align__(16) float rs[4], rq[4];
  const int wave = tid >> 6, lane = tid & 63;
  if (lane == 0) {
    rs[wave] = s;
    rq[wave] = sq;
  }
  __syncthreads();
  if (tid == 0) {
    const float S1 = rs[0] + rs[1] + rs[2] + rs[3];
    const float S2 = rq[0] + rq[1] + rq[2] + rq[3];
    const float mean = S1 * (1.f / 1024.f);
    const float var = fmaxf(0.f, (S2 - 1024.f * mean * mean) * (1.f / 1023.f));
    const float rstd = 1.f / (sqrtf(var) + 1e-6f);
    st[row] = make_float2(mean, rstd);
  }
}

template <int EPI, int NORM, int AF32, int OUTF32>
__global__ __launch_bounds__(256) void gemm_bt(
    const void* __restrict__ Ap, const float* __restrict__ W,
    const float* __restrict__ bias, const float* __restrict__ resid,
    void* __restrict__ outp, const float2* __restrict__ stats,
    const float* __restrict__ alpha_p, const float* __restrict__ beta_p,
    int M, int N, int K, int ldw) {
  __shared__ __align__(16) unsigned short As[128 * 32];
  __shared__ __align__(16) unsigned short Bs[128 * 32];
  const int tid = threadIdx.x;
  const int lane = tid & 63, wave = tid >> 6;
  const int quad = lane >> 4, l16 = lane & 15;
  const int m0 = blockIdx.y * 128, n0 = blockIdx.x * 128;
  const int wm = (wave >> 1) * 64, wn = (wave & 1) * 64;

  float alpha = 0.f, beta = 0.f;
  if (NORM) {
    alpha = alpha_p[0];
    beta = beta_p[0];
  }

  f32x4 acc[4][4];
#pragma unroll
  for (int i = 0; i < 4; i++)
#pragma unroll
    for (int j = 0; j < 4; j++) acc[i][j] = {0.f, 0.f, 0.f, 0.f};

  const int rA = tid >> 2;
  const int kc = (tid & 3) * 8;

  for (int k0 = 0; k0 < K; k0 += 32) {
    ushort8 av[2], bv8[2];
#pragma unroll
    for (int i = 0; i < 2; i++) {
      const int row = i * 64 + rA;
      if (AF32) {
        const float* ap = (const float*)Ap + (size_t)(m0 + row) * K + k0 + kc;
        f32x4 a0 = *(const f32x4*)ap;
        f32x4 a1 = *(const f32x4*)(ap + 4);
        if (NORM) {
          const float2 st = stats[m0 + row];
#pragma unroll
          for (int j = 0; j < 4; j++) {
            a0[j] = alpha * (a0[j] - st.x) * st.y + beta;
            a1[j] = alpha * (a1[j] - st.x) * st.y + beta;
          }
        }
#pragma unroll
        for (int j = 0; j < 4; j++) {
          av[i][j] = f2b(a0[j]);
          av[i][j + 4] = f2b(a1[j]);
        }
      } else {
        av[i] = *(const ushort8*)((const unsigned short*)Ap +
                                  (size_t)(m0 + row) * K + k0 + kc);
      }
      const float* wp = W + (size_t)(n0 + row) * ldw + k0 + kc;
      f32x4 w0 = *(const f32x4*)wp;
      f32x4 w1 = *(const f32x4*)(wp + 4);
#pragma unroll
      for (int j = 0; j < 4; j++) {
        bv8[i][j] = f2b(w0[j]);
        bv8[i][j + 4] = f2b(w1[j]);
      }
    }
    __syncthreads();
#pragma unroll
    for (int i = 0; i < 2; i++) {
      const int row = i * 64 + rA;
      *(ushort8*)&As[row * 32 + kc] = av[i];
      *(ushort8*)&Bs[row * 32 + kc] = bv8[i];
    }
    __syncthreads();
    short8 af[4], bf[4];
#pragma unroll
    for (int t = 0; t < 4; t++) {
      af[t] = *(const short8*)&As[(wm + t * 16 + l16) * 32 + quad * 8];
      bf[t] = *(const short8*)&Bs[(wn + t * 16 + l16) * 32 + quad * 8];
    }
#pragma unroll
    for (int mt = 0; mt < 4; mt++)
#pragma unroll
      for (int nt = 0; nt < 4; nt++) acc[mt][nt] = mfma16(af[mt], bf[nt], acc[mt][nt]);
  }

#pragma unroll
  for (int nt = 0; nt < 4; nt++) {
    const int col = n0 + wn + nt * 16 + l16;
    const float bv = (EPI == 3) ? 0.f : bias[col];
#pragma unroll
    for (int mt = 0; mt < 4; mt++) {
#pragma unroll
      for (int r = 0; r < 4; r++) {
        const int row = m0 + wm + mt * 16 + quad * 4 + r;
        float v = acc[mt][nt][r] + bv;
        if (EPI == 2) v = fmaxf(v, 0.f);
        if (EPI == 4) {
          const size_t vtidx =
              ((size_t)((row >> 11) * 1024 + col)) * 2048 + (row & 2047);
          ((unsigned short*)outp)[vtidx] = f2b(v);
        } else {
          const size_t idx = (size_t)row * N + col;
          if (EPI == 1 || EPI == 3) v += resid[idx];
          if (OUTF32)
            ((float*)outp)[idx] = v;
          else
            ((unsigned short*)outp)[idx] = f2b(v);
        }
      }
    }
  }
}

// ---------------------------------------------------------------------------
extern "C" void kernel_launch(void* const* d_in, const int* in_sizes, int n_in,
                              void* d_out, int out_size, void* d_ws, size_t ws_size,
                              hipStream_t stream) {
  (void)in_sizes; (void)n_in; (void)out_size;
  const float* x  = (const float*)d_in[0];
  const int* mask = (const int*)d_in[1];
  const float* wq = (const float*)d_in[2];
  const float* bq = (const float*)d_in[3];
  const float* wk = (const float*)d_in[4];
  const float* bk = (const float*)d_in[5];
  const float* wv = (const float*)d_in[6];
  const float* bv = (const float*)d_in[7];
  const float* wo = (const float*)d_in[8];
  const float* bo = (const float*)d_in[9];
  const float* w1 = (const float*)d_in[10];
  const float* b1 = (const float*)d_in[11];
  const float* w2 = (const float*)d_in[12];
  const float* b2 = (const float*)d_in[13];
  const float* a1 = (const float*)d_in[14];
  const float* c1 = (const float*)d_in[15];
  const float* a2 = (const float*)d_in[16];
  const float* c2 = (const float*)d_in[17];

  char* ws = (char*)d_ws;
  const size_t MB = 1 << 20;
  const int M = B * S;  // 8192
  dim3 blk(256);
  dim3 gAttn(S / 128, B * H);  // (16, 64)

  if (ws_size >= 89 * MB) {
    const int tier3 = (ws_size >= 152 * MB);
    const int tier2 = (ws_size >= 121 * MB);
    unsigned short* wqkv_b = (unsigned short*)(ws + 0);        // 6 MB
    unsigned short* wo_b   = (unsigned short*)(ws + 6 * MB);   // 2 MB
    unsigned short* w1_b   = (unsigned short*)(ws + 8 * MB);   // 8 MB
    unsigned short* w2_b   = (unsigned short*)(ws + 16 * MB);  // 8 MB
    unsigned short* ln1x   = (unsigned short*)(ws + 25 * MB);  // 16 MB
    unsigned short* q      = (unsigned short*)(ws + 41 * MB);  // 16 MB
    unsigned short* kk     = (unsigned short*)(ws + 57 * MB);  // 16 MB
    unsigned short* vt     = (unsigned short*)(ws + 73 * MB);  // 16 MB
    float*          hbuf   = (float*)(ws + 57 * MB);           // 32 MB (over kk+vt)
    unsigned short* ln2x   = (unsigned short*)(ws + 25 * MB);  // over ln1x
    unsigned short* ffn1q  = (unsigned short*)(ws + 41 * MB);  // over q (tier1)
    unsigned short* ffn1h  = (unsigned short*)(ws + 89 * MB);  // 32 MB (tier2)
    unsigned short* ffn1f  = (unsigned short*)(ws + 89 * MB);  // 64 MB (tier3)
    float* outb = (float*)d_out;

    // weights -> bf16, one batched dispatch
    CvtArgs ca;
    ca.s[0] = wq; ca.d[0] = wqkv_b;            ca.n[0] = 1048576;
    ca.s[1] = wk; ca.d[1] = wqkv_b + 1048576;  ca.n[1] = 1048576;
    ca.s[2] = wv; ca.d[2] = wqkv_b + 2097152;  ca.n[2] = 1048576;
    ca.s[3] = wo; ca.d[3] = wo_b;              ca.n[3] = 1048576;
    ca.s[4] = w1; ca.d[4] = w1_b;              ca.n[4] = 4194304;
    ca.s[5] = w2; ca.d[5] = w2_b;              ca.n[5] = 4194304;
    convert6<<<dim3(4096, 6), blk, 0, stream>>>(ca);

    ln_fused<<<M, blk, 0, stream>>>(x, a1, c1, ln1x);
    gemm_bb<4><<<dim3(24, 64), blk, 0, stream>>>(ln1x, wqkv_b, bq, bk, bv, nullptr,
                                                 q, kk, vt, M, 3072, D, D);
    attn_kernel<<<gAttn, blk, 0, stream>>>(q, kk, vt, mask);
    gemm_bb64<1><<<dim3(8, 64), blk, 0, stream>>>(q, wo_b, bo, x, hbuf, M, D, D, D);
    ln_fused<<<M, blk, 0, stream>>>(hbuf, a2, c2, ln2x);

    if (tier3) {
      // one full FFN1 (N=4096) + one full-K FFN2 (K=4096, BK=64 kernel)
      gemm_bb<2><<<dim3(32, 64), blk, 0, stream>>>(ln2x, w1_b, b1, nullptr, nullptr,
                                                   nullptr, ffn1f, nullptr, nullptr,
                                                   M, DFF, D, D);
      gemm_bb64<1><<<dim3(8, 64), blk, 0, stream>>>(ffn1f, w2_b, b2, hbuf, outb,
                                                    M, D, DFF, DFF);
    } else if (tier2) {
      gemm_bb<2><<<dim3(16, 64), blk, 0, stream>>>(ln2x, w1_b, b1, nullptr, nullptr,
                                                   nullptr, ffn1h, nullptr, nullptr,
                                                   M, 2048, D, D);
      gemm_bb64<1><<<dim3(8, 64), blk, 0, stream>>>(ffn1h, w2_b, b2, hbuf, outb,
                                                    M, D, 2048, DFF);
      gemm_bb<2><<<dim3(16, 64), blk, 0, stream>>>(ln2x, w1_b + (size_t)2048 * D,
                                                   b1 + 2048, nullptr, nullptr, nullptr,
                                                   ffn1h, nullptr, nullptr, M, 2048, D, D);
      gemm_bb64<3><<<dim3(8, 64), blk, 0, stream>>>(ffn1h, w2_b + 2048, nullptr, outb,
                                                    outb, M, D, 2048, DFF);
    } else {
      for (int i = 0; i < 4; i++) {
        gemm_bb<2><<<dim3(8, 64), blk, 0, stream>>>(ln2x, w1_b + (size_t)i * 1024 * D,
                                                    b1 + i * 1024, nullptr, nullptr,
                                                    nullptr, ffn1q, nullptr, nullptr,
                                                    M, 1024, D, D);
        if (i == 0)
          gemm_bb64<1><<<dim3(8, 64), blk, 0, stream>>>(ffn1q, w2_b + i * 1024, b2,
                                                        hbuf, outb, M, D, 1024, DFF);
        else
          gemm_bb64<3><<<dim3(8, 64), blk, 0, stream>>>(ffn1q, w2_b + i * 1024, nullptr,
                                                        outb, outb, M, D, 1024, DFF);
      }
    }
  } else {
    // fallback (round-5 structure, 49 MB peak)
    float2* stats1 = (float2*)(ws + 0);
    float2* stats2 = (float2*)(ws + 128 * 1024);
    unsigned short* q    = (unsigned short*)(ws + 1 * MB);
    unsigned short* kk   = (unsigned short*)(ws + 17 * MB);
    unsigned short* vt   = (unsigned short*)(ws + 33 * MB);
    float*          hbuf = (float*)(ws + 17 * MB);
    unsigned short* ffn1 = (unsigned short*)(ws + 1 * MB);
    float* outb = (float*)d_out;
    dim3 gD(D / 128, M / 128);

    stats_kernel<<<M, blk, 0, stream>>>(x, stats1);
    gemm_bt<0, 1, 1, 0><<<gD, blk, 0, stream>>>(x, wq, bq, nullptr, q, stats1, a1, c1, M, D, D, D);
    gemm_bt<0, 1, 1, 0><<<gD, blk, 0, stream>>>(x, wk, bk, nullptr, kk, stats1, a1, c1, M, D, D, D);
    gemm_bt<4, 1, 1, 0><<<gD, blk, 0, stream>>>(x, wv, bv, nullptr, vt, stats1, a1, c1, M, D, D, D);
    attn_kernel<<<gAttn, blk, 0, stream>>>(q, kk, vt, mask);
    gemm_bt<1, 0, 0, 1><<<gD, blk, 0, stream>>>(q, wo, bo, x, hbuf, nullptr, nullptr, nullptr, M, D, D, D);
    stats_kernel<<<M, blk, 0, stream>>>(hbuf, stats2);
    for (int i = 0; i < 4; i++) {
      gemm_bt<2, 1, 1, 0><<<gD, blk, 0, stream>>>(hbuf, w1 + (size_t)i * 1024 * D,
                                                  b1 + i * 1024, nullptr, ffn1, stats2,
                                                  a2, c2, M, 1024, D, D);
      if (i == 0)
        gemm_bt<1, 0, 0, 1><<<gD, blk, 0, stream>>>(ffn1, w2 + i * 1024, b2, hbuf, outb,
                                                    nullptr, nullptr, nullptr, M, D, 1024, DFF);
      else
        gemm_bt<3, 0, 0, 1><<<gD, blk, 0, stream>>>(ffn1, w2 + i * 1024, nullptr, outb, outb,
                                                    nullptr, nullptr, nullptr, M, D, 1024, DFF);
    }
  }
}

// Round 6
// 543.612 us; speedup vs baseline: 1.1702x; 1.0094x over previous
//
#include <hip/hip_runtime.h>
#include <math.h>

static constexpr int B  = 4;
static constexpr int S  = 2048;
static constexpr int D  = 1024;
static constexpr int H  = 16;
static constexpr int DFF = 4096;

typedef __attribute__((ext_vector_type(8))) short short8;
typedef __attribute__((ext_vector_type(8))) unsigned short ushort8;
typedef __attribute__((ext_vector_type(4))) unsigned short ushort4v;
typedef __attribute__((ext_vector_type(4))) float f32x4;

__device__ __forceinline__ float b2f(unsigned short u) {
  unsigned int x = ((unsigned int)u) << 16;
  float f;
  __builtin_memcpy(&f, &x, 4);
  return f;
}
__device__ __forceinline__ unsigned short f2b(float f) {
  unsigned int x;
  __builtin_memcpy(&x, &f, 4);
  x += 0x7fffu + ((x >> 16) & 1u);  // round-to-nearest-even
  return (unsigned short)(x >> 16);
}

// packed f32x2 -> bf16x2 (RNE), single VALU op (no builtin on gfx950)
__device__ __forceinline__ unsigned int cvtpk_bf16(float lo, float hi) {
  unsigned int r;
  asm("v_cvt_pk_bf16_f32 %0, %1, %2" : "=v"(r) : "v"(lo), "v"(hi));
  return r;
}

__device__ __forceinline__ f32x4 mfma16(short8 a, short8 b, f32x4 c) {
  return __builtin_amdgcn_mfma_f32_16x16x32_bf16(a, b, c, 0, 0, 0);
}

// global -> LDS direct copy, 16B per lane (wave-uniform base + lane*16).
__device__ __forceinline__ void gload_lds16(const void* gsrc, void* ldst) {
  __builtin_amdgcn_global_load_lds(
      (__attribute__((address_space(1))) void*)(uintptr_t)gsrc,
      (__attribute__((address_space(3))) void*)ldst, 16, 0, 0);
}

#define VMC0 asm volatile("s_waitcnt vmcnt(0)" ::: "memory")
#define SB0  __builtin_amdgcn_sched_barrier(0)
#define BAR  __builtin_amdgcn_s_barrier()
#define PRIO1 __builtin_amdgcn_s_setprio(1)
#define PRIO0 __builtin_amdgcn_s_setprio(0)

// XCD-aware bijective block swizzle (requires nwg % 8 == 0): contiguous
// work-tile chunks per XCD -> shared A/W panels hit the same L2. [T1]
__device__ __forceinline__ int xcd_swz(int wg, int nwg) {
  if (!(nwg & 7)) wg = (wg & 7) * (nwg >> 3) + (wg >> 3);
  return wg;
}

// ---------------------------------------------------------------------------
// Batched f32 -> bf16 convert: 6 segments, grid (maxblocks, 6)
// ---------------------------------------------------------------------------
struct CvtArgs {
  const float* s[6];
  unsigned short* d[6];
  int n[6];
};
__global__ __launch_bounds__(256) void convert6(CvtArgs a) {
  const int seg = blockIdx.y;
  const int i = (blockIdx.x * 256 + threadIdx.x) * 4;
  if (i < a.n[seg]) {
    f32x4 v = *(const f32x4*)(a.s[seg] + i);
    ushort4v o;
#pragma unroll
    for (int j = 0; j < 4; j++) o[j] = f2b(v[j]);
    *(ushort4v*)(a.d[seg] + i) = o;
  }
}

// ---------------------------------------------------------------------------
// Fused LayerNorm (f32 in -> bf16 out): alpha*(x-mean)/(std+eps)+beta, ddof=1
// ---------------------------------------------------------------------------
__global__ __launch_bounds__(256) void ln_fused(const float* __restrict__ x,
                                                const float* __restrict__ ap,
                                                const float* __restrict__ cp,
                                                unsigned short* __restrict__ out) {
  const int row = blockIdx.x, tid = threadIdx.x;
  const size_t base = (size_t)row * D;
  float v[4];
  float s = 0.f, sq = 0.f;
#pragma unroll
  for (int i = 0; i < 4; i++) {
    v[i] = x[base + tid + i * 256];
    s += v[i];
    sq += v[i] * v[i];
  }
#pragma unroll
  for (int o = 32; o > 0; o >>= 1) {
    s += __shfl_xor(s, o);
    sq += __shfl_xor(sq, o);
  }
  __shared__ __align__(16) float rs[4], rq[4];
  const int wave = tid >> 6, lane = tid & 63;
  if (lane == 0) {
    rs[wave] = s;
    rq[wave] = sq;
  }
  __syncthreads();
  const float S1 = rs[0] + rs[1] + rs[2] + rs[3];
  const float S2 = rq[0] + rq[1] + rq[2] + rq[3];
  const float mean = S1 * (1.f / 1024.f);
  const float var = fmaxf(0.f, (S2 - 1024.f * mean * mean) * (1.f / 1023.f));
  const float rstd = 1.f / (sqrtf(var) + 1e-6f);
  const float alpha = ap[0], beta = cp[0];
#pragma unroll
  for (int i = 0; i < 4; i++)
    out[base + tid + i * 256] = f2b(alpha * (v[i] - mean) * rstd + beta);
}

// ---------------------------------------------------------------------------
// Pure-bf16 GEMM (m97 structure + XCD swizzle): C = A @ W^T. 128x128 tile,
// BK=32, 4 waves, 4x4 MFMA frags. Used by the FALLBACK path only.
// ---------------------------------------------------------------------------
template <int EPI>
__global__ __launch_bounds__(256) void gemm_bb(
    const unsigned short* __restrict__ A, const unsigned short* __restrict__ W,
    const float* __restrict__ bias0, const float* __restrict__ bias1,
    const float* __restrict__ bias2, const float* __restrict__ resid,
    void* __restrict__ out, unsigned short* __restrict__ outK,
    unsigned short* __restrict__ outV, int M, int N, int K, int ldw) {
  __shared__ __align__(16) unsigned short As[128 * 32];
  __shared__ __align__(16) unsigned short Bs[128 * 32];
  const int tid = threadIdx.x;
  const int lane = tid & 63, wave = tid >> 6;
  const int quad = lane >> 4, l16 = lane & 15;
  const int nbx = gridDim.x;
  const int wg = xcd_swz(blockIdx.y * nbx + blockIdx.x, nbx * gridDim.y);
  const int m0 = (wg / nbx) * 128, n0 = (wg % nbx) * 128;
  const int wm = (wave >> 1) * 64, wn = (wave & 1) * 64;

  f32x4 acc[4][4];
#pragma unroll
  for (int i = 0; i < 4; i++)
#pragma unroll
    for (int j = 0; j < 4; j++) acc[i][j] = {0.f, 0.f, 0.f, 0.f};

  const int rA = tid >> 2;       // 0..63 row within half-tile
  const int kc = (tid & 3) * 8;  // 8-elem (16B) chunk

  for (int k0 = 0; k0 < K; k0 += 32) {
    __syncthreads();
#pragma unroll
    for (int i = 0; i < 2; i++) {
      const int row = i * 64 + rA;
      gload_lds16(&A[(size_t)(m0 + row) * K + k0 + kc], &As[(i * 256 + wave * 64) * 8]);
      gload_lds16(&W[(size_t)(n0 + row) * ldw + k0 + kc], &Bs[(i * 256 + wave * 64) * 8]);
    }
    __syncthreads();
    short8 af[4], bf[4];
#pragma unroll
    for (int t = 0; t < 4; t++) {
      af[t] = *(const short8*)&As[(wm + t * 16 + l16) * 32 + quad * 8];
      bf[t] = *(const short8*)&Bs[(wn + t * 16 + l16) * 32 + quad * 8];
    }
#pragma unroll
    for (int mt = 0; mt < 4; mt++)
#pragma unroll
      for (int nt = 0; nt < 4; nt++) acc[mt][nt] = mfma16(af[mt], bf[nt], acc[mt][nt]);
  }

  if (EPI == 4) {
    const int band = (n0 + wn) >> 10;
    const float* bp = band == 0 ? bias0 : (band == 1 ? bias1 : bias2);
#pragma unroll
    for (int nt = 0; nt < 4; nt++) {
      const int col = n0 + wn + nt * 16 + l16;
      const int cl = col & 1023;
      const float bv = bp[cl];
#pragma unroll
      for (int mt = 0; mt < 4; mt++) {
#pragma unroll
        for (int r = 0; r < 4; r++) {
          const int row = m0 + wm + mt * 16 + quad * 4 + r;
          const float v = acc[mt][nt][r] + bv;
          if (band == 0)
            ((unsigned short*)out)[(size_t)row * 1024 + cl] = f2b(v);
          else if (band == 1)
            outK[(size_t)row * 1024 + cl] = f2b(v);
          else
            outV[((size_t)((row >> 11) * 1024 + cl)) * 2048 + (row & 2047)] = f2b(v);
        }
      }
    }
  } else {
#pragma unroll
    for (int nt = 0; nt < 4; nt++) {
      const int col = n0 + wn + nt * 16 + l16;
      const float bv = (EPI == 3) ? 0.f : bias0[col];
#pragma unroll
      for (int mt = 0; mt < 4; mt++) {
#pragma unroll
        for (int r = 0; r < 4; r++) {
          const int row = m0 + wm + mt * 16 + quad * 4 + r;
          const size_t idx = (size_t)row * N + col;
          float v = acc[mt][nt][r] + bv;
          if (EPI == 2) {
            v = fmaxf(v, 0.f);
            ((unsigned short*)out)[idx] = f2b(v);
          } else {
            v += resid[idx];
            ((float*)out)[idx] = v;
          }
        }
      }
    }
  }
}

// ---------------------------------------------------------------------------
// BK=64 GEMM (primary): 128x128 tile, 32 MFMA per barrier-pair (half the
// vmcnt(0)+barrier drains of BK=32 per K-element — the r5 FFN2 A/B showed
// ~30% win). XOR-chunk-swizzled LDS (128B rows): pre-swizzled global source
// + linear gload_lds dest, read c = (kh*4+quad)^(l16&7); 8 lanes per 4-bank
// group x 16B = 8 cy = b128 throughput minimum (no extra serialization).
// + XCD swizzle. EPI semantics identical to gemm_bb. Requires K % 64 == 0.
// ---------------------------------------------------------------------------
template <int EPI>
__global__ __launch_bounds__(256) void gemm_bb64(
    const unsigned short* __restrict__ A, const unsigned short* __restrict__ W,
    const float* __restrict__ bias0, const float* __restrict__ bias1,
    const float* __restrict__ bias2, const float* __restrict__ resid,
    void* __restrict__ out, unsigned short* __restrict__ outK,
    unsigned short* __restrict__ outV, int M, int N, int K, int ldw) {
  __shared__ __align__(16) unsigned short As[128 * 64];
  __shared__ __align__(16) unsigned short Bs[128 * 64];
  const int tid = threadIdx.x;
  const int lane = tid & 63, wave = tid >> 6;
  const int quad = lane >> 4, l16 = lane & 15;
  const int nbx = gridDim.x;
  const int wg = xcd_swz(blockIdx.y * nbx + blockIdx.x, nbx * gridDim.y);
  const int m0 = (wg / nbx) * 128, n0 = (wg % nbx) * 128;
  const int wm = (wave >> 1) * 64, wn = (wave & 1) * 64;

  f32x4 acc[4][4];
#pragma unroll
  for (int i = 0; i < 4; i++)
#pragma unroll
    for (int j = 0; j < 4; j++) acc[i][j] = {0.f, 0.f, 0.f, 0.f};

  // staging: lane -> row group sr = lane>>3, chunk pre-swizzled
  const int sr = lane >> 3;
  const int sc = ((lane & 7) ^ sr) * 8;
  // frag read: swizzled chunk offsets (row&7 == l16&7 for frag rows)
  const int xr = l16 & 7;
  const int c0 = (quad ^ xr) * 8;        // kh = 0
  const int c1 = ((4 + quad) ^ xr) * 8;  // kh = 1

  for (int k0 = 0; k0 < K; k0 += 64) {
    __syncthreads();
#pragma unroll
    for (int j = 0; j < 4; j++) {
      const int row = j * 32 + wave * 8 + sr;
      gload_lds16(&A[(size_t)(m0 + row) * K + k0 + sc], &As[(j * 32 + wave * 8) * 64]);
      gload_lds16(&W[(size_t)(n0 + row) * ldw + k0 + sc], &Bs[(j * 32 + wave * 8) * 64]);
    }
    __syncthreads();
    short8 af[4][2], bf[4][2];
#pragma unroll
    for (int t = 0; t < 4; t++) {
      af[t][0] = *(const short8*)&As[(wm + t * 16 + l16) * 64 + c0];
      af[t][1] = *(const short8*)&As[(wm + t * 16 + l16) * 64 + c1];
      bf[t][0] = *(const short8*)&Bs[(wn + t * 16 + l16) * 64 + c0];
      bf[t][1] = *(const short8*)&Bs[(wn + t * 16 + l16) * 64 + c1];
    }
#pragma unroll
    for (int mt = 0; mt < 4; mt++)
#pragma unroll
      for (int nt = 0; nt < 4; nt++) {
        acc[mt][nt] = mfma16(af[mt][0], bf[nt][0], acc[mt][nt]);
        acc[mt][nt] = mfma16(af[mt][1], bf[nt][1], acc[mt][nt]);
      }
  }

  if (EPI == 4) {
    const int band = (n0 + wn) >> 10;
    const float* bp = band == 0 ? bias0 : (band == 1 ? bias1 : bias2);
#pragma unroll
    for (int nt = 0; nt < 4; nt++) {
      const int col = n0 + wn + nt * 16 + l16;
      const int cl = col & 1023;
      const float bv = bp[cl];
#pragma unroll
      for (int mt = 0; mt < 4; mt++) {
#pragma unroll
        for (int r = 0; r < 4; r++) {
          const int row = m0 + wm + mt * 16 + quad * 4 + r;
          const float v = acc[mt][nt][r] + bv;
          if (band == 0)
            ((unsigned short*)out)[(size_t)row * 1024 + cl] = f2b(v);
          else if (band == 1)
            outK[(size_t)row * 1024 + cl] = f2b(v);
          else
            outV[((size_t)((row >> 11) * 1024 + cl)) * 2048 + (row & 2047)] = f2b(v);
        }
      }
    }
  } else {
#pragma unroll
    for (int nt = 0; nt < 4; nt++) {
      const int col = n0 + wn + nt * 16 + l16;
      const float bv = (EPI == 3) ? 0.f : bias0[col];
#pragma unroll
      for (int mt = 0; mt < 4; mt++) {
#pragma unroll
        for (int r = 0; r < 4; r++) {
          const int row = m0 + wm + mt * 16 + quad * 4 + r;
          const size_t idx = (size_t)row * N + col;
          float v = acc[mt][nt][r] + bv;
          if (EPI == 2) {
            v = fmaxf(v, 0.f);
            ((unsigned short*)out)[idx] = f2b(v);
          } else {
            v += resid[idx];
            ((float*)out)[idx] = v;
          }
        }
      }
    }
  }
}

// ---------------------------------------------------------------------------
// Flash attention v4: QBLK=32 per wave (128 q-rows/block, grid (S/128, B*H)),
// single-buffered [64][64] K/V staged via global_load_lds with XOR chunk
// swizzle (rule 21). K-frags shared across the wave's two q-groups (4 MFMAs
// per K-read), V-frags shared (2 MFMAs per V-read), mask decode shared.
// ---------------------------------------------------------------------------
__device__ __forceinline__ void attn_stage(const unsigned short* Kg,
                                           const unsigned short* Vg,
                                           unsigned short* Kd, unsigned short* Vd,
                                           int kt) {
  gload_lds16(Kg + (size_t)kt * 64 * D, Kd);
  gload_lds16(Kg + (size_t)kt * 64 * D + 8 * (size_t)D, Kd + 8 * 64);
  gload_lds16(Vg + (size_t)kt * 64, Vd);
  gload_lds16(Vg + (size_t)kt * 64 + 8 * (size_t)S, Vd + 8 * 64);
}

__global__ __launch_bounds__(256, 4) void attn_kernel(unsigned short* __restrict__ Q,
                                                      const unsigned short* __restrict__ Kb,
                                                      const unsigned short* __restrict__ VT,
                                                      const int* __restrict__ mask) {
  __shared__ __align__(16) unsigned short Ks[64 * 64];
  __shared__ __align__(16) unsigned short Vs[64 * 64];
  constexpr int PPAD = 72;
  __shared__ __align__(16) unsigned short Pb[8][16 * PPAD];  // [wave*2+qh]

  const int tid = threadIdx.x, lane = tid & 63, wave = tid >> 6;
  const int quad = lane >> 4, l16 = lane & 15;
  const int q0 = blockIdx.x * 128;
  const int b = blockIdx.y >> 4, h = blockIdx.y & 15;

  const int sr = lane >> 3;
  const int sc8 = ((lane & 7) ^ sr) * 8;
  const unsigned short* Kg = Kb + ((size_t)b * S + wave * 16 + sr) * D + h * 64 + sc8;
  const unsigned short* Vg = VT + ((size_t)blockIdx.y * 64 + wave * 16 + sr) * S + sc8;
  unsigned short* Kd = &Ks[(wave * 16) * 64];
  unsigned short* Vd = &Vs[(wave * 16) * 64];

  short8 qf[2][2];
#pragma unroll
  for (int qh = 0; qh < 2; qh++) {
    const unsigned short* qp =
        &Q[((size_t)b * S + q0 + wave * 32 + qh * 16 + l16) * D + h * 64 + quad * 8];
    qf[qh][0] = *(const short8*)qp;
    qf[qh][1] = *(const short8*)(qp + 32);
  }

  float l_acc[2] = {0.f, 0.f};
  f32x4 o_acc[2][4];
#pragma unroll
  for (int qh = 0; qh < 2; qh++)
#pragma unroll
    for (int t = 0; t < 4; t++) o_acc[qh][t] = {0.f, 0.f, 0.f, 0.f};

  const int xr = l16 & 7;
  const int c0 = (quad ^ xr) * 8;
  const int c1 = ((quad + 4) ^ xr) * 8;

  for (int kt = 0; kt < S / 64; kt++) {
    const int k0 = kt * 64;
    BAR;  // all waves' reads of previous tile complete
    attn_stage(Kg, Vg, Kd, Vd, kt);
    VMC0;
    SB0;
    BAR;  // staged data visible to all waves

    // S^T = K Q^T for BOTH q-groups: each kf pair feeds 4 MFMAs
    f32x4 sc4[2][4];
#pragma unroll
    for (int qh = 0; qh < 2; qh++)
#pragma unroll
      for (int nt = 0; nt < 4; nt++) sc4[qh][nt] = {0.f, 0.f, 0.f, 0.f};
    PRIO1;
#pragma unroll
    for (int nt = 0; nt < 4; nt++) {
      short8 kf0 = *(const short8*)&Ks[(nt * 16 + l16) * 64 + c0];
      short8 kf1 = *(const short8*)&Ks[(nt * 16 + l16) * 64 + c1];
      sc4[0][nt] = mfma16(kf0, qf[0][0], sc4[0][nt]);
      sc4[0][nt] = mfma16(kf1, qf[0][1], sc4[0][nt]);
      sc4[1][nt] = mfma16(kf0, qf[1][0], sc4[1][nt]);
      sc4[1][nt] = mfma16(kf1, qf[1][1], sc4[1][nt]);
    }
    PRIO0;

    // softmax: mask decode shared across q-groups; cvt_pk pack, b64 writes
#pragma unroll
    for (int nt = 0; nt < 4; nt++) {
      const int4 mv = *(const int4*)&mask[b * S + k0 + nt * 16 + quad * 4];
      const float m0f = mv.x ? -12.f : -42.f;
      const float m1f = mv.y ? -12.f : -42.f;
      const float m2f = mv.z ? -12.f : -42.f;
      const float m3f = mv.w ? -12.f : -42.f;
#pragma unroll
      for (int qh = 0; qh < 2; qh++) {
        const float p0 = __expf(fmaf(sc4[qh][nt][0], 0.125f, m0f));
        const float p1 = __expf(fmaf(sc4[qh][nt][1], 0.125f, m1f));
        const float p2 = __expf(fmaf(sc4[qh][nt][2], 0.125f, m2f));
        const float p3 = __expf(fmaf(sc4[qh][nt][3], 0.125f, m3f));
        l_acc[qh] += (p0 + p1) + (p2 + p3);
        uint2 pw;
        pw.x = cvtpk_bf16(p0, p1);
        pw.y = cvtpk_bf16(p2, p3);
        *(uint2*)&Pb[wave * 2 + qh][l16 * PPAD + nt * 16 + quad * 4] = pw;
      }
    }

    // P @ V: vf pair shared across q-groups (2 MFMAs per V-read)
    short8 pf[2][2];
#pragma unroll
    for (int qh = 0; qh < 2; qh++) {
      pf[qh][0] = *(const short8*)&Pb[wave * 2 + qh][l16 * PPAD + quad * 8];
      pf[qh][1] = *(const short8*)&Pb[wave * 2 + qh][l16 * PPAD + 32 + quad * 8];
    }
    PRIO1;
#pragma unroll
    for (int nt = 0; nt < 4; nt++) {
      short8 vf0 = *(const short8*)&Vs[(nt * 16 + l16) * 64 + c0];
      short8 vf1 = *(const short8*)&Vs[(nt * 16 + l16) * 64 + c1];
      o_acc[0][nt] = mfma16(pf[0][0], vf0, o_acc[0][nt]);
      o_acc[0][nt] = mfma16(pf[0][1], vf1, o_acc[0][nt]);
      o_acc[1][nt] = mfma16(pf[1][0], vf0, o_acc[1][nt]);
      o_acc[1][nt] = mfma16(pf[1][1], vf1, o_acc[1][nt]);
    }
    PRIO0;
  }

  // l: sum across quads; normalize + store per q-group
#pragma unroll
  for (int qh = 0; qh < 2; qh++) {
    float la = l_acc[qh];
    la += __shfl_xor(la, 16);
    la += __shfl_xor(la, 32);
#pragma unroll
    for (int r = 0; r < 4; r++) {
      const float lr = __shfl(la, quad * 4 + r);
      const float inv = 1.f / lr;
      const int q = q0 + wave * 32 + qh * 16 + quad * 4 + r;
#pragma unroll
      for (int nt = 0; nt < 4; nt++) {
        const int dk = nt * 16 + l16;
        Q[((size_t)b * S + q) * D + h * 64 + dk] = f2b(o_acc[qh][nt][r] * inv);
      }
    }
  }
}

// ---------------------------------------------------------------------------
// FALLBACK path (ws < 89MB): round-5 kernels
// ---------------------------------------------------------------------------
__global__ __launch_bounds__(256) void stats_kernel(const float* __restrict__ x,
                                                    float2* __restrict__ st) {
  const int row = blockIdx.x, tid = threadIdx.x;
  const size_t base = (size_t)row * D;
  float s = 0.f, sq = 0.f;
#pragma unroll
  for (int i = 0; i < 4; i++) {
    const float v = x[base + tid + i * 256];
    s += v;
    sq += v * v;
  }
#pragma unroll
  for (int o = 32; o > 0; o >>= 1) {
    s += __shfl_xor(s, o);
    sq += __shfl_xor(sq, o);
  }
  __shared__ __align__(16) float rs[4], rq[4];
  const int wave = tid >> 6, lane = tid & 63;
  if (lane == 0) {
    rs[wave] = s;
    rq[wave] = sq;
  }
  __syncthreads();
  if (tid == 0) {
    const float S1 = rs[0] + rs[1] + rs[2] + rs[3];
    const float S2 = rq[0] + rq[1] + rq[2] + rq[3];
    const float mean = S1 * (1.f / 1024.f);
    const float var = fmaxf(0.f, (S2 - 1024.f * mean * mean) * (1.f / 1023.f));
    const float rstd = 1.f / (sqrtf(var) + 1e-6f);
    st[row] = make_float2(mean, rstd);
  }
}

template <int EPI, int NORM, int AF32, int OUTF32>
__global__ __launch_bounds__(256) void gemm_bt(
    const void* __restrict__ Ap, const float* __restrict__ W,
    const float* __restrict__ bias, const float* __restrict__ resid,
    void* __restrict__ outp, const float2* __restrict__ stats,
    const float* __restrict__ alpha_p, const float* __restrict__ beta_p,
    int M, int N, int K, int ldw) {
  __shared__ __align__(16) unsigned short As[128 * 32];
  __shared__ __align__(16) unsigned short Bs[128 * 32];
  const int tid = threadIdx.x;
  const int lane = tid & 63, wave = tid >> 6;
  const int quad = lane >> 4, l16 = lane & 15;
  const int m0 = blockIdx.y * 128, n0 = blockIdx.x * 128;
  const int wm = (wave >> 1) * 64, wn = (wave & 1) * 64;

  float alpha = 0.f, beta = 0.f;
  if (NORM) {
    alpha = alpha_p[0];
    beta = beta_p[0];
  }

  f32x4 acc[4][4];
#pragma unroll
  for (int i = 0; i < 4; i++)
#pragma unroll
    for (int j = 0; j < 4; j++) acc[i][j] = {0.f, 0.f, 0.f, 0.f};

  const int rA = tid >> 2;
  const int kc = (tid & 3) * 8;

  for (int k0 = 0; k0 < K; k0 += 32) {
    ushort8 av[2], bv8[2];
#pragma unroll
    for (int i = 0; i < 2; i++) {
      const int row = i * 64 + rA;
      if (AF32) {
        const float* ap = (const float*)Ap + (size_t)(m0 + row) * K + k0 + kc;
        f32x4 a0 = *(const f32x4*)ap;
        f32x4 a1 = *(const f32x4*)(ap + 4);
        if (NORM) {
          const float2 st = stats[m0 + row];
#pragma unroll
          for (int j = 0; j < 4; j++) {
            a0[j] = alpha * (a0[j] - st.x) * st.y + beta;
            a1[j] = alpha * (a1[j] - st.x) * st.y + beta;
          }
        }
#pragma unroll
        for (int j = 0; j < 4; j++) {
          av[i][j] = f2b(a0[j]);
          av[i][j + 4] = f2b(a1[j]);
        }
      } else {
        av[i] = *(const ushort8*)((const unsigned short*)Ap +
                                  (size_t)(m0 + row) * K + k0 + kc);
      }
      const float* wp = W + (size_t)(n0 + row) * ldw + k0 + kc;
      f32x4 w0 = *(const f32x4*)wp;
      f32x4 w1 = *(const f32x4*)(wp + 4);
#pragma unroll
      for (int j = 0; j < 4; j++) {
        bv8[i][j] = f2b(w0[j]);
        bv8[i][j + 4] = f2b(w1[j]);
      }
    }
    __syncthreads();
#pragma unroll
    for (int i = 0; i < 2; i++) {
      const int row = i * 64 + rA;
      *(ushort8*)&As[row * 32 + kc] = av[i];
      *(ushort8*)&Bs[row * 32 + kc] = bv8[i];
    }
    __syncthreads();
    short8 af[4], bf[4];
#pragma unroll
    for (int t = 0; t < 4; t++) {
      af[t] = *(const short8*)&As[(wm + t * 16 + l16) * 32 + quad * 8];
      bf[t] = *(const short8*)&Bs[(wn + t * 16 + l16) * 32 + quad * 8];
    }
#pragma unroll
    for (int mt = 0; mt < 4; mt++)
#pragma unroll
      for (int nt = 0; nt < 4; nt++) acc[mt][nt] = mfma16(af[mt], bf[nt], acc[mt][nt]);
  }

#pragma unroll
  for (int nt = 0; nt < 4; nt++) {
    const int col = n0 + wn + nt * 16 + l16;
    const float bv = (EPI == 3) ? 0.f : bias[col];
#pragma unroll
    for (int mt = 0; mt < 4; mt++) {
#pragma unroll
      for (int r = 0; r < 4; r++) {
        const int row = m0 + wm + mt * 16 + quad * 4 + r;
        float v = acc[mt][nt][r] + bv;
        if (EPI == 2) v = fmaxf(v, 0.f);
        if (EPI == 4) {
          const size_t vtidx =
              ((size_t)((row >> 11) * 1024 + col)) * 2048 + (row & 2047);
          ((unsigned short*)outp)[vtidx] = f2b(v);
        } else {
          const size_t idx = (size_t)row * N + col;
          if (EPI == 1 || EPI == 3) v += resid[idx];
          if (OUTF32)
            ((float*)outp)[idx] = v;
          else
            ((unsigned short*)outp)[idx] = f2b(v);
        }
      }
    }
  }
}

// ---------------------------------------------------------------------------
extern "C" void kernel_launch(void* const* d_in, const int* in_sizes, int n_in,
                              void* d_out, int out_size, void* d_ws, size_t ws_size,
                              hipStream_t stream) {
  (void)in_sizes; (void)n_in; (void)out_size;
  const float* x  = (const float*)d_in[0];
  const int* mask = (const int*)d_in[1];
  const float* wq = (const float*)d_in[2];
  const float* bq = (const float*)d_in[3];
  const float* wk = (const float*)d_in[4];
  const float* bk = (const float*)d_in[5];
  const float* wv = (const float*)d_in[6];
  const float* bv = (const float*)d_in[7];
  const float* wo = (const float*)d_in[8];
  const float* bo = (const float*)d_in[9];
  const float* w1 = (const float*)d_in[10];
  const float* b1 = (const float*)d_in[11];
  const float* w2 = (const float*)d_in[12];
  const float* b2 = (const float*)d_in[13];
  const float* a1 = (const float*)d_in[14];
  const float* c1 = (const float*)d_in[15];
  const float* a2 = (const float*)d_in[16];
  const float* c2 = (const float*)d_in[17];

  char* ws = (char*)d_ws;
  const size_t MB = 1 << 20;
  const int M = B * S;  // 8192
  dim3 blk(256);
  dim3 gAttn(S / 128, B * H);  // (16, 64)

  if (ws_size >= 89 * MB) {
    const int tier3 = (ws_size >= 152 * MB);
    const int tier2 = (ws_size >= 121 * MB);
    unsigned short* wqkv_b = (unsigned short*)(ws + 0);        // 6 MB
    unsigned short* wo_b   = (unsigned short*)(ws + 6 * MB);   // 2 MB
    unsigned short* w1_b   = (unsigned short*)(ws + 8 * MB);   // 8 MB
    unsigned short* w2_b   = (unsigned short*)(ws + 16 * MB);  // 8 MB
    unsigned short* ln1x   = (unsigned short*)(ws + 25 * MB);  // 16 MB
    unsigned short* q      = (unsigned short*)(ws + 41 * MB);  // 16 MB
    unsigned short* kk     = (unsigned short*)(ws + 57 * MB);  // 16 MB
    unsigned short* vt     = (unsigned short*)(ws + 73 * MB);  // 16 MB
    float*          hbuf   = (float*)(ws + 57 * MB);           // 32 MB (over kk+vt)
    unsigned short* ln2x   = (unsigned short*)(ws + 25 * MB);  // over ln1x
    unsigned short* ffn1q  = (unsigned short*)(ws + 41 * MB);  // over q (tier1)
    unsigned short* ffn1h  = (unsigned short*)(ws + 89 * MB);  // 32 MB (tier2)
    unsigned short* ffn1f  = (unsigned short*)(ws + 89 * MB);  // 64 MB (tier3)
    float* outb = (float*)d_out;

    // weights -> bf16, one batched dispatch
    CvtArgs ca;
    ca.s[0] = wq; ca.d[0] = wqkv_b;            ca.n[0] = 1048576;
    ca.s[1] = wk; ca.d[1] = wqkv_b + 1048576;  ca.n[1] = 1048576;
    ca.s[2] = wv; ca.d[2] = wqkv_b + 2097152;  ca.n[2] = 1048576;
    ca.s[3] = wo; ca.d[3] = wo_b;              ca.n[3] = 1048576;
    ca.s[4] = w1; ca.d[4] = w1_b;              ca.n[4] = 4194304;
    ca.s[5] = w2; ca.d[5] = w2_b;              ca.n[5] = 4194304;
    convert6<<<dim3(4096, 6), blk, 0, stream>>>(ca);

    ln_fused<<<M, blk, 0, stream>>>(x, a1, c1, ln1x);
    gemm_bb64<4><<<dim3(24, 64), blk, 0, stream>>>(ln1x, wqkv_b, bq, bk, bv, nullptr,
                                                   q, kk, vt, M, 3072, D, D);
    attn_kernel<<<gAttn, blk, 0, stream>>>(q, kk, vt, mask);
    gemm_bb64<1><<<dim3(8, 64), blk, 0, stream>>>(q, wo_b, bo, nullptr, nullptr, x,
                                                  hbuf, nullptr, nullptr, M, D, D, D);
    ln_fused<<<M, blk, 0, stream>>>(hbuf, a2, c2, ln2x);

    if (tier3) {
      // one full FFN1 (N=4096) + one full-K FFN2 (K=4096), both BK=64
      gemm_bb64<2><<<dim3(32, 64), blk, 0, stream>>>(ln2x, w1_b, b1, nullptr, nullptr,
                                                     nullptr, ffn1f, nullptr, nullptr,
                                                     M, DFF, D, D);
      gemm_bb64<1><<<dim3(8, 64), blk, 0, stream>>>(ffn1f, w2_b, b2, nullptr, nullptr,
                                                    hbuf, outb, nullptr, nullptr,
                                                    M, D, DFF, DFF);
    } else if (tier2) {
      gemm_bb64<2><<<dim3(16, 64), blk, 0, stream>>>(ln2x, w1_b, b1, nullptr, nullptr,
                                                     nullptr, ffn1h, nullptr, nullptr,
                                                     M, 2048, D, D);
      gemm_bb64<1><<<dim3(8, 64), blk, 0, stream>>>(ffn1h, w2_b, b2, nullptr, nullptr,
                                                    hbuf, outb, nullptr, nullptr,
                                                    M, D, 2048, DFF);
      gemm_bb64<2><<<dim3(16, 64), blk, 0, stream>>>(ln2x, w1_b + (size_t)2048 * D,
                                                     b1 + 2048, nullptr, nullptr, nullptr,
                                                     ffn1h, nullptr, nullptr, M, 2048, D, D);
      gemm_bb64<3><<<dim3(8, 64), blk, 0, stream>>>(ffn1h, w2_b + 2048, nullptr, nullptr,
                                                    nullptr, outb, outb, nullptr, nullptr,
                                                    M, D, 2048, DFF);
    } else {
      for (int i = 0; i < 4; i++) {
        gemm_bb64<2><<<dim3(8, 64), blk, 0, stream>>>(ln2x, w1_b + (size_t)i * 1024 * D,
                                                      b1 + i * 1024, nullptr, nullptr,
                                                      nullptr, ffn1q, nullptr, nullptr,
                                                      M, 1024, D, D);
        if (i == 0)
          gemm_bb64<1><<<dim3(8, 64), blk, 0, stream>>>(ffn1q, w2_b + i * 1024, b2,
                                                        nullptr, nullptr, hbuf, outb,
                                                        nullptr, nullptr, M, D, 1024, DFF);
        else
          gemm_bb64<3><<<dim3(8, 64), blk, 0, stream>>>(ffn1q, w2_b + i * 1024, nullptr,
                                                        nullptr, nullptr, outb, outb,
                                                        nullptr, nullptr, M, D, 1024, DFF);
      }
    }
  } else {
    // fallback (round-5 structure, 49 MB peak)
    float2* stats1 = (float2*)(ws + 0);
    float2* stats2 = (float2*)(ws + 128 * 1024);
    unsigned short* q    = (unsigned short*)(ws + 1 * MB);
    unsigned short* kk   = (unsigned short*)(ws + 17 * MB);
    unsigned short* vt   = (unsigned short*)(ws + 33 * MB);
    float*          hbuf = (float*)(ws + 17 * MB);
    unsigned short* ffn1 = (unsigned short*)(ws + 1 * MB);
    float* outb = (float*)d_out;
    dim3 gD(D / 128, M / 128);

    stats_kernel<<<M, blk, 0, stream>>>(x, stats1);
    gemm_bt<0, 1, 1, 0><<<gD, blk, 0, stream>>>(x, wq, bq, nullptr, q, stats1, a1, c1, M, D, D, D);
    gemm_bt<0, 1, 1, 0><<<gD, blk, 0, stream>>>(x, wk, bk, nullptr, kk, stats1, a1, c1, M, D, D, D);
    gemm_bt<4, 1, 1, 0><<<gD, blk, 0, stream>>>(x, wv, bv, nullptr, vt, stats1, a1, c1, M, D, D, D);
    attn_kernel<<<gAttn, blk, 0, stream>>>(q, kk, vt, mask);
    gemm_bt<1, 0, 0, 1><<<gD, blk, 0, stream>>>(q, wo, bo, x, hbuf, nullptr, nullptr, nullptr, M, D, D, D);
    stats_kernel<<<M, blk, 0, stream>>>(hbuf, stats2);
    for (int i = 0; i < 4; i++) {
      gemm_bt<2, 1, 1, 0><<<gD, blk, 0, stream>>>(hbuf, w1 + (size_t)i * 1024 * D,
                                                  b1 + i * 1024, nullptr, ffn1, stats2,
                                                  a2, c2, M, 1024, D, D);
      if (i == 0)
        gemm_bt<1, 0, 0, 1><<<gD, blk, 0, stream>>>(ffn1, w2 + i * 1024, b2, hbuf, outb,
                                                    nullptr, nullptr, nullptr, M, D, 1024, DFF);
      else
        gemm_bt<3, 0, 0, 1><<<gD, blk, 0, stream>>>(ffn1, w2 + i * 1024, nullptr, outb, outb,
                                                    nullptr, nullptr, nullptr, M, D, 1024, DFF);
    }
  }
}